// Round 16
// baseline (205.731 us; speedup 1.0000x reference)
//
#include <hip/hip_runtime.h>

#define LOG2E 1.4426950408889634f
#define TANH_S 2.8853900817779268f  // 2*log2(e)
#define NB 4
#define NL 256
#define ND 256
#define NH 256

typedef __attribute__((ext_vector_type(8))) short s16x8;
typedef __attribute__((ext_vector_type(4))) short s16x4;
typedef __attribute__((ext_vector_type(4))) float f32x4;
typedef __attribute__((ext_vector_type(2))) unsigned int u32x2;
typedef __attribute__((ext_vector_type(4))) unsigned int u32x4;

static __device__ __forceinline__ float b2f(unsigned short u) {
  return __builtin_bit_cast(float, (unsigned int)u << 16);
}
static __device__ __forceinline__ unsigned short f2b(float f) {
  unsigned int x = __builtin_bit_cast(unsigned int, f);
  return (unsigned short)((x + 0x7fffu + ((x >> 16) & 1u)) >> 16);
}
static __device__ __forceinline__ unsigned int cvtpk(float lo, float hi) {
  unsigned int r;
  asm("v_cvt_pk_bf16_f32 %0, %1, %2" : "=v"(r) : "v"(lo), "v"(hi));
  return r;
}

// ws layout (5.75 MB):
//   X    fp32 [0,      1M)    : Hq@Wb
//   EC1  fp32 [1M,     2M)    : exp2(TANH_S*(Hq@Wc1))
//   EM1  fp32 [2M,     3M)    : exp2(TANH_S*(Hq@Wm))
//   AF   bf16 [3M,   3.5M)    : Hq packed in MFMA A-fragment order
//   C2b  bf16 [3.5M,   4M)    : (Hp@Wc2)*TANH_S
//   M2b  bf16 [4M,   4.5M)    : (Hp@Wm)*TANH_S
//   WT   bf16 [4.5M, 5.5M)    : 4x transposed+split weights [n][k]:
//                               w=0 Wc1*S, 1 Wm*S, 2 Wb, 3 Wc2*S (hi+lo 128K each)
//   WdT  fp32 [5.5M, 5.75M)   : (Wd^T)*TANH_S  [h][k] (256 KB)

__global__ void __launch_bounds__(256) prep(
    const float* __restrict__ Hq,
    const float* __restrict__ Wc1, const float* __restrict__ Wc2,
    const float* __restrict__ Wb, const float* __restrict__ Wm,
    const float* __restrict__ Wd, float* __restrict__ ws)
{
  const int which = blockIdx.y;  // 0=AF 1=WdT 2=WT transpose+split
  const int tid = threadIdx.x;
  __shared__ __align__(16) float a_s[8][256];
  if (which == 0) {
    // pack bf16(Hq) into MFMA A-fragment order:
    // AF[((((b*4+w)*4+mt)*8+kt)*64 + quad*16 + c16)*8 + j]
    const int m0 = blockIdx.x * 8;
    unsigned short* AF = (unsigned short*)((char*)ws + 3145728);
    const int row = m0 + (tid >> 5);
    const int grp = tid & 31;
    const int kt = grp >> 2, quad = grp & 3;
    const int k0 = kt * 32 + quad * 8;
    const int bb = row >> 8, q = row & 255;
    const int w = q >> 6, mt = (q >> 4) & 3, c16 = q & 15;
    const float* src = Hq + row * ND + k0;
    f32x4 v0 = *(const f32x4*)(src);
    f32x4 v1 = *(const f32x4*)(src + 4);
    s16x8 o;
    #pragma unroll
    for (int j = 0; j < 4; ++j) { o[j] = (short)f2b(v0[j]); o[4 + j] = (short)f2b(v1[j]); }
    *(s16x8*)(AF + ((((bb * 4 + w) * 4 + mt) * 8 + kt) * 64 + quad * 16 + c16) * 8) = o;
    return;
  }
  if (which == 1) {
    // transpose Wd -> WdT[h][k] fp32 (prescaled by TANH_S) via LDS
    if (blockIdx.x >= 32) return;
    const int k0 = blockIdx.x * 8;
    #pragma unroll
    for (int kk = 0; kk < 8; ++kk)
      a_s[kk][tid] = Wd[(k0 + kk) * NH + tid] * TANH_S;
    __syncthreads();
    float* WdT = (float*)((char*)ws + 5767168);
    f32x4 v0 = {a_s[0][tid], a_s[1][tid], a_s[2][tid], a_s[3][tid]};
    f32x4 v1 = {a_s[4][tid], a_s[5][tid], a_s[6][tid], a_s[7][tid]};
    *(f32x4*)(WdT + tid * 256 + k0) = v0;
    *(f32x4*)(WdT + tid * 256 + k0 + 4) = v1;
    return;
  }
  // which == 2: transpose + bf16-split the 4 score weights
  const int w = blockIdx.x >> 5;          // 0..3
  const int k0 = (blockIdx.x & 31) * 8;
  const float* W = (w == 0) ? Wc1 : (w == 1) ? Wm : (w == 2) ? Wb : Wc2;
  const float scale = (w == 2) ? 1.0f : TANH_S;
  #pragma unroll
  for (int kk = 0; kk < 8; ++kk)
    a_s[kk][tid] = W[(k0 + kk) * NH + tid] * scale;
  __syncthreads();
  unsigned short* WT = (unsigned short*)((char*)ws + 4718592) + w * 131072;
  s16x8 hi, lo;
  #pragma unroll
  for (int kk = 0; kk < 8; ++kk) {
    float v = a_s[kk][tid];
    unsigned short h = f2b(v);
    hi[kk] = (short)h;
    lo[kk] = (short)f2b(v - b2f(h));
  }
  *(s16x8*)(WT + tid * 256 + k0) = hi;
  *(s16x8*)(WT + 65536 + tid * 256 + k0) = lo;
}

// ---- all 5 prep GEMMs via split-bf16 MFMA, LDS-staged weights.
// grid (16 rowtiles, 8 coltiles, 5 matrices) = 640 blocks; tile 64 rows x 32 cols.
// z: 0=EC1(Hq,w0,exp2) 1=EM1(Hq,w1,exp2) 2=X(Hq,w2) 3=C2b(Hp,w3) 4=M2b(Hp,w1)
__global__ void __launch_bounds__(256) gemm5(
    const float* __restrict__ Hq, const float* __restrict__ Hp,
    float* __restrict__ ws)
{
  const int rt = blockIdx.x, ct = blockIdx.y, mz = blockIdx.z;
  const int tid = threadIdx.x;
  const int wave = tid >> 6, lane = tid & 63;
  const int quad = lane >> 4, c16 = lane & 15;

  __shared__ __align__(16) char bs[32768];  // BsH 16K | BsL 16K
  char* BsH = bs;
  char* BsL = bs + 16384;

  const int w = (mz == 4) ? 1 : ((mz == 3) ? 3 : mz);
  const float* A = (mz >= 3) ? Hp : Hq;
  const int n0 = ct * 32;

  { // stage WH/WL rows [n0, n0+32) x k[0,256) into LDS with XOR swizzle
    const unsigned short* WTw = (const unsigned short*)((const char*)ws + 4718592)
                                + w * 131072 + n0 * 256;
    const int soff = (tid & 31) * 16;
    #pragma unroll
    for (int i = 0; i < 4; ++i) {
      const int h = i * 8 + (tid >> 5);
      const int doff = h * 512 + (soff ^ ((h & 7) * 16));
      u32x4 vh = *(const u32x4*)((const char*)WTw + h * 512 + soff);
      u32x4 vl = *(const u32x4*)((const char*)WTw + 131072 + h * 512 + soff);
      *(u32x4*)(BsH + doff) = vh;
      *(u32x4*)(BsL + doff) = vl;
    }
  }

  // A fragments: row = rt*64 + wave*16 + c16, split hi/lo
  const int row = rt * 64 + wave * 16 + c16;
  s16x8 ah[8], al[8];
  #pragma unroll
  for (int kt = 0; kt < 8; ++kt) {
    const float* src = A + row * ND + kt * 32 + quad * 8;
    f32x4 v0 = *(const f32x4*)(src);
    f32x4 v1 = *(const f32x4*)(src + 4);
    #pragma unroll
    for (int j = 0; j < 4; ++j) {
      unsigned short h0 = f2b(v0[j]);
      ah[kt][j] = (short)h0;
      al[kt][j] = (short)f2b(v0[j] - b2f(h0));
      unsigned short h1 = f2b(v1[j]);
      ah[kt][4 + j] = (short)h1;
      al[kt][4 + j] = (short)f2b(v1[j] - b2f(h1));
    }
  }
  __syncthreads();

  f32x4 acc[2];
  #pragma unroll
  for (int nt = 0; nt < 2; ++nt) acc[nt] = f32x4{0.f, 0.f, 0.f, 0.f};

  const int xswz = (c16 & 7) * 16;
  #pragma unroll
  for (int kt = 0; kt < 8; ++kt) {
    #pragma unroll
    for (int nt = 0; nt < 2; ++nt) {
      const int baddr = (nt * 16 + c16) * 512 + ((kt * 64 + quad * 16) ^ xswz);
      s16x8 bh = *(const s16x8*)(BsH + baddr);
      s16x8 bl = *(const s16x8*)(BsL + baddr);
      acc[nt] = __builtin_amdgcn_mfma_f32_16x16x32_bf16(ah[kt], bh, acc[nt], 0, 0, 0);
      acc[nt] = __builtin_amdgcn_mfma_f32_16x16x32_bf16(al[kt], bh, acc[nt], 0, 0, 0);
      acc[nt] = __builtin_amdgcn_mfma_f32_16x16x32_bf16(ah[kt], bl, acc[nt], 0, 0, 0);
    }
  }

  const int orow0 = rt * 64 + wave * 16 + quad * 4;
  if (mz == 2) {  // X fp32
    #pragma unroll
    for (int nt = 0; nt < 2; ++nt)
      #pragma unroll
      for (int r = 0; r < 4; ++r)
        ws[(orow0 + r) * NH + n0 + nt * 16 + c16] = acc[nt][r];
  } else if (mz < 2) {  // EC1 / EM1: store exp2 of scaled score part, fp32
    float* E = (float*)((char*)ws + (mz == 0 ? 1048576 : 2097152));
    #pragma unroll
    for (int nt = 0; nt < 2; ++nt)
      #pragma unroll
      for (int r = 0; r < 4; ++r)
        E[(orow0 + r) * NH + n0 + nt * 16 + c16] =
            __builtin_amdgcn_exp2f(acc[nt][r]);
  } else {  // C2b / M2b bf16
    unsigned short* O = (unsigned short*)((char*)ws +
        (mz == 3 ? 3670016 : 4194304));
    #pragma unroll
    for (int nt = 0; nt < 2; ++nt)
      #pragma unroll
      for (int r = 0; r < 4; ++r)
        O[(orow0 + r) * NH + n0 + nt * 16 + c16] = f2b(acc[nt][r]);
  }
}

// ---- merged: branch-d MFMA GEMM + tanh reduce, then scores c/b/m,
// softmax(all 4), attend(all 4). One block per (b,p); d-scores stay in LDS.
// v16: h-tile 32 (8 ht iters), acc[4][2] (32 VGPR) — shrink phase-1 live set
// so natural allocation lands in (64,128] with ZERO spill (R14/R15: forced
// 64-reg budget spilled ~30MB/dispatch; R13: natural 132 crossed the cliff).
// Bs 16KB -> block LDS ~25.6KB -> LDS allows 6 blocks/CU.
__global__ void __launch_bounds__(256) dfused(
    const float* __restrict__ Hp, const float* __restrict__ Hq,
    const float* __restrict__ vd, const float* __restrict__ vc,
    const float* __restrict__ vm, const float* __restrict__ ws,
    float* __restrict__ out)
{
  const int p = blockIdx.x, b = blockIdx.y;
  const int tid = threadIdx.x;
  const int wave = tid >> 6, lane = tid & 63;
  const int quad = lane >> 4, c16 = lane & 15;

  __shared__ __align__(16) char ovl[20480];
  __shared__ __align__(16) float sc4[4 * 256];  // rows: 0=c 1=b 2=d 3=m
  __shared__ __align__(16) float hp_s[256];
  __shared__ __align__(16) float invsum[4];

  short* Bs = (short*)ovl;                       // 16 KB, dphase
  float* vd2_s = (float*)(ovl + 16384);          // 1 KB, dphase
  float* redp = (float*)ovl;                     // 16 KB, fphase
  float* e2c_s = (float*)(ovl + 16384);          // fphase: exp2(c2s)
  float* e2m_s = (float*)(ovl + 17408);          // fphase: exp2(-m2s)
  float* vc2_s = (float*)(ovl + 18432);
  float* vm2_s = (float*)(ovl + 19456);

  const unsigned short* AF = (const unsigned short*)((const char*)ws + 3145728);
  const float* WdT = (const float*)((const char*)ws + 5767168);
  const float* X = ws;
  const float* EC1 = (const float*)((const char*)ws + 1048576);
  const float* EM1 = (const float*)((const char*)ws + 2097152);
  const unsigned short* C2b = (const unsigned short*)((const char*)ws + 3670016);
  const unsigned short* M2b = (const unsigned short*)((const char*)ws + 4194304);

  hp_s[tid] = Hp[(b * NL + p) * ND + tid];
  __syncthreads();

  // ======== phase 1: branch d (h-tile 32, acc[4][2]) ====
  {
    // vd2 staged AFTER hp_s barrier (vd2_s aliases nothing in dphase)
    vd2_s[tid] = 2.0f * vd[tid];

    const int scol = (tid & 63) * 4;
    const f32x4 hpv = *(const f32x4*)(hp_s + scol);
    const int wq0 = wave * 64;
    const unsigned short* AFw = AF + (b * 4 + wave) * 4 * 8 * 64 * 8;
    const int xswz = (c16 & 7) * 16;

    float sdp[4][4];
    #pragma unroll
    for (int mt = 0; mt < 4; ++mt)
      #pragma unroll
      for (int r = 0; r < 4; ++r) sdp[mt][r] = 0.f;
    float vs2 = 0.f;

    for (int ht = 0; ht < 8; ++ht) {
      const int h0 = ht * 32;
      __syncthreads();
      { // stage Bs[h][k] = bf16(WdT[h0+h][k]*hp[k]), h in [0,32)
        const float* wsrc = WdT + h0 * 256 + tid * 4;
        #pragma unroll
        for (int i = 0; i < 8; ++i) {
          f32x4 wv = *(const f32x4*)(wsrc + i * 1024);
          const int h = i * 4 + (tid >> 6);
          const unsigned int u0 = cvtpk(wv[0] * hpv[0], wv[1] * hpv[1]);
          const unsigned int u1 = cvtpk(wv[2] * hpv[2], wv[3] * hpv[3]);
          const int baddr = h * 512 + (((tid & 63) * 8) ^ ((h & 7) * 16));
          *(u32x2*)((char*)Bs + baddr) = u32x2{u0, u1};
        }
      }
      __syncthreads();

      f32x4 acc[4][2];
      #pragma unroll
      for (int mt = 0; mt < 4; ++mt)
        #pragma unroll
        for (int nt = 0; nt < 2; ++nt) acc[mt][nt] = f32x4{0.f, 0.f, 0.f, 0.f};

      #pragma unroll 2
      for (int kt = 0; kt < 8; ++kt) {
        const int koff = (kt * 64 + quad * 16) ^ xswz;
        s16x8 b0 = *(const s16x8*)((const char*)Bs + c16 * 512 + koff);
        s16x8 b1 = *(const s16x8*)((const char*)Bs + (16 + c16) * 512 + koff);
        #pragma unroll
        for (int mt = 0; mt < 4; ++mt) {
          s16x8 a8 = *(const s16x8*)(AFw + ((mt * 8 + kt) * 64 + lane) * 8);
          acc[mt][0] = __builtin_amdgcn_mfma_f32_16x16x32_bf16(
              a8, b0, acc[mt][0], 0, 0, 0);
          acc[mt][1] = __builtin_amdgcn_mfma_f32_16x16x32_bf16(
              a8, b1, acc[mt][1], 0, 0, 0);
        }
      }

      // vd*tanh(z) = vd - vd2*rcp(e^{2z}+1); acc already 2*log2e*z
      #pragma unroll
      for (int nt = 0; nt < 2; ++nt) {
        const float v2 = vd2_s[h0 + nt * 16 + c16];
        vs2 += v2;
        #pragma unroll
        for (int mt = 0; mt < 4; ++mt) {
          #pragma unroll
          for (int r = 0; r < 4; ++r) {
            float e = __builtin_amdgcn_exp2f(acc[mt][nt][r]);
            sdp[mt][r] += v2 * __builtin_amdgcn_rcpf(e + 1.0f);
          }
        }
      }
    }

    // deferred 16-lane reduce -> d-scores into sc4[512+q]
    #pragma unroll
    for (int m = 1; m < 16; m <<= 1) vs2 += __shfl_xor(vs2, m, 64);
    #pragma unroll
    for (int mt = 0; mt < 4; ++mt)
      #pragma unroll
      for (int r = 0; r < 4; ++r) {
        float v = sdp[mt][r];
        #pragma unroll
        for (int m = 1; m < 16; m <<= 1) v += __shfl_xor(v, m, 64);
        if (c16 == 0)
          sc4[512 + wq0 + mt * 16 + quad * 4 + r] = 0.5f * vs2 - v;
      }
  }
  __syncthreads();  // Bs dead; overlay becomes fphase arrays

  { // fphase LDS loads; one exp2 per thread folds c2/m2 into multipliers
    const int r = (b * NL + p) * ND + tid;
    e2c_s[tid] = __builtin_amdgcn_exp2f(b2f(C2b[r]));
    e2m_s[tid] = __builtin_amdgcn_exp2f(-b2f(M2b[r]));
    vc2_s[tid] = 2.0f * vc[tid];
    vm2_s[tid] = 2.0f * vm[tid];
  }
  __syncthreads();

  // ======== phase 2: scores c, b, m (no exp2 in inner loop) =============
  {
    const int qsub = lane >> 4;
    const int hb = c16 * 4;
    float lc = 0.f, lm = 0.f;
    #pragma unroll
    for (int hi = 0; hi < 4; ++hi) {
      const int h = hb + hi * 64;
      #pragma unroll
      for (int i = 0; i < 4; ++i) { lc += vc2_s[h + i]; lm += vm2_s[h + i]; }
    }
    #pragma unroll
    for (int m = 1; m < 16; m <<= 1) {
      lc += __shfl_xor(lc, m, 64);
      lm += __shfl_xor(lm, m, 64);
    }
    const float c0 = 0.5f * lc, m0 = 0.5f * lm;

    for (int qg = 0; qg < 16; ++qg) {
      const int q = wave * 64 + qg * 4 + qsub;
      const float* ecr = EC1 + (b * NL + q) * NH;
      const float* emr = EM1 + (b * NL + q) * NH;
      const float* xr  = X + (b * NL + q) * ND;
      float pcr0 = 0.f, pmr0 = 0.f, pb0 = 0.f;
      float pcr1 = 0.f, pmr1 = 0.f, pb1 = 0.f;
      #pragma unroll
      for (int hi = 0; hi < 4; ++hi) {
        const int h = hb + hi * 64;
        f32x4 ec = *(const f32x4*)(ecr + h);
        f32x4 em = *(const f32x4*)(emr + h);
        f32x4 xv = *(const f32x4*)(xr + h);
        #pragma unroll
        for (int i = 0; i < 4; ++i) {
          float tc = ec[i] * e2c_s[h + i] + 1.0f;
          float tm = em[i] * e2m_s[h + i] + 1.0f;
          if (i & 1) {
            pcr1 += vc2_s[h + i] * __builtin_amdgcn_rcpf(tc);
            pmr1 += vm2_s[h + i] * __builtin_amdgcn_rcpf(tm);
            pb1 += hp_s[h + i] * xv[i];
          } else {
            pcr0 += vc2_s[h + i] * __builtin_amdgcn_rcpf(tc);
            pmr0 += vm2_s[h + i] * __builtin_amdgcn_rcpf(tm);
            pb0 += hp_s[h + i] * xv[i];
          }
        }
      }
      float pcr = pcr0 + pcr1, pmr = pmr0 + pmr1, pb = pb0 + pb1;
      #pragma unroll
      for (int m = 1; m < 16; m <<= 1) {
        pcr += __shfl_xor(pcr, m, 64);
        pmr += __shfl_xor(pmr, m, 64);
        pb  += __shfl_xor(pb, m, 64);
      }
      if (c16 == 0) {
        sc4[q]       = c0 - pcr;
        sc4[256 + q] = pb;
        sc4[768 + q] = m0 - pmr;
      }
    }
  }
  __syncthreads();

  // ======== phase 3: softmax; wave w owns branch w ======================
  {
    float s0 = sc4[wave * 256 + lane];
    float s1 = sc4[wave * 256 + lane + 64];
    float s2 = sc4[wave * 256 + lane + 128];
    float s3 = sc4[wave * 256 + lane + 192];
    float mx = fmaxf(fmaxf(s0, s1), fmaxf(s2, s3));
    #pragma unroll
    for (int m = 1; m < 64; m <<= 1) mx = fmaxf(mx, __shfl_xor(mx, m, 64));
    float e0 = __builtin_amdgcn_exp2f((s0 - mx) * LOG2E);
    float e1 = __builtin_amdgcn_exp2f((s1 - mx) * LOG2E);
    float e2 = __builtin_amdgcn_exp2f((s2 - mx) * LOG2E);
    float e3 = __builtin_amdgcn_exp2f((s3 - mx) * LOG2E);
    float sm = e0 + e1 + e2 + e3;
    #pragma unroll
    for (int m = 1; m < 64; m <<= 1) sm += __shfl_xor(sm, m, 64);
    sc4[wave * 256 + lane]       = e0;
    sc4[wave * 256 + lane + 64]  = e1;
    sc4[wave * 256 + lane + 128] = e2;
    sc4[wave * 256 + lane + 192] = e3;
    if (lane == 0) invsum[wave] = __builtin_amdgcn_rcpf(sm);
  }
  __syncthreads();

  // ======== phase 4: attend =============================================
  {
    const int q0 = wave * 64;
    f32x4 pa0 = {0.f,0.f,0.f,0.f}, pa1 = {0.f,0.f,0.f,0.f};
    f32x4 pa2 = {0.f,0.f,0.f,0.f}, pa3 = {0.f,0.f,0.f,0.f};
    for (int qi = 0; qi < 64; ++qi) {
      const int q = q0 + qi;
      const float ac = sc4[q];
      const float ab = sc4[256 + q];
      const float ad = sc4[512 + q];
      const float am = sc4[768 + q];
      f32x4 hv = *(const f32x4*)(Hq + (b * NL + q) * ND + lane * 4);
      pa0 += ac * hv; pa1 += ab * hv; pa2 += ad * hv; pa3 += am * hv;
    }
    *(f32x4*)(redp + (wave * 4 + 0) * 256 + lane * 4) = pa0;
    *(f32x4*)(redp + (wave * 4 + 1) * 256 + lane * 4) = pa1;
    *(f32x4*)(redp + (wave * 4 + 2) * 256 + lane * 4) = pa2;
    *(f32x4*)(redp + (wave * 4 + 3) * 256 + lane * 4) = pa3;
  }
  __syncthreads();

  // ======== phase 5: cross-wave reduce + normalize + store ==============
  {
    #pragma unroll
    for (int br = 0; br < 4; ++br) {
      float s = redp[(0 * 4 + br) * 256 + tid] + redp[(1 * 4 + br) * 256 + tid]
              + redp[(2 * 4 + br) * 256 + tid] + redp[(3 * 4 + br) * 256 + tid];
      out[((br * NB + b) * NL + p) * ND + tid] = s * invsum[br];
    }
  }
}

extern "C" void kernel_launch(void* const* d_in, const int* in_sizes, int n_in,
                              void* d_out, int out_size, void* d_ws, size_t ws_size,
                              hipStream_t stream) {
  const float* Hp  = (const float*)d_in[0];
  const float* Hq  = (const float*)d_in[1];
  const float* Wc1 = (const float*)d_in[2];
  const float* Wc2 = (const float*)d_in[3];
  const float* vc  = (const float*)d_in[4];
  const float* Wb  = (const float*)d_in[5];
  const float* Wd  = (const float*)d_in[6];
  const float* vd  = (const float*)d_in[7];
  const float* Wm  = (const float*)d_in[8];
  const float* vm  = (const float*)d_in[9];
  float* ws = (float*)d_ws;
  float* out = (float*)d_out;

  hipLaunchKernelGGL(prep, dim3(128, 3), dim3(256), 0, stream,
                     Hq, Wc1, Wc2, Wb, Wm, Wd, ws);
  hipLaunchKernelGGL(gemm5, dim3(16, 8, 5), dim3(256), 0, stream,
                     Hq, Hp, ws);
  hipLaunchKernelGGL(dfused, dim3(256, 4), dim3(256), 0, stream,
                     Hp, Hq, vd, vc, vm, ws, out);
}

// Round 17
// 182.047 us; speedup vs baseline: 1.1301x; 1.1301x over previous
//
#include <hip/hip_runtime.h>

#define LOG2E 1.4426950408889634f
#define TANH_S 2.8853900817779268f  // 2*log2(e)
#define NB 4
#define NL 256
#define ND 256
#define NH 256

typedef __attribute__((ext_vector_type(8))) short s16x8;
typedef __attribute__((ext_vector_type(4))) short s16x4;
typedef __attribute__((ext_vector_type(4))) float f32x4;
typedef __attribute__((ext_vector_type(2))) unsigned int u32x2;
typedef __attribute__((ext_vector_type(4))) unsigned int u32x4;

static __device__ __forceinline__ float b2f(unsigned short u) {
  return __builtin_bit_cast(float, (unsigned int)u << 16);
}
static __device__ __forceinline__ unsigned short f2b(float f) {
  unsigned int x = __builtin_bit_cast(unsigned int, f);
  return (unsigned short)((x + 0x7fffu + ((x >> 16) & 1u)) >> 16);
}
static __device__ __forceinline__ unsigned int cvtpk(float lo, float hi) {
  unsigned int r;
  asm("v_cvt_pk_bf16_f32 %0, %1, %2" : "=v"(r) : "v"(lo), "v"(hi));
  return r;
}

// ws layout (5.75 MB):
//   X    fp32 [0,      1M)    : Hq@Wb
//   EC1  bf16 [1M,   1.5M)    : bf16(exp2(TANH_S*(Hq@Wc1)))
//   EM1  bf16 [1.5M,   2M)    : bf16(exp2(TANH_S*(Hq@Wm)))
//   AF   bf16 [3M,   3.5M)    : Hq packed in MFMA A-fragment order
//   C2b  bf16 [3.5M,   4M)    : (Hp@Wc2)*TANH_S
//   M2b  bf16 [4M,   4.5M)    : (Hp@Wm)*TANH_S
//   WT   bf16 [4.5M, 5.5M)    : 4x transposed+split weights [n][k]:
//                               w=0 Wc1*S, 1 Wm*S, 2 Wb, 3 Wc2*S (hi+lo 128K each)
//   WdT  fp32 [5.5M, 5.75M)   : (Wd^T)*TANH_S  [h][k] (256 KB)

__global__ void __launch_bounds__(256) prep(
    const float* __restrict__ Hq,
    const float* __restrict__ Wc1, const float* __restrict__ Wc2,
    const float* __restrict__ Wb, const float* __restrict__ Wm,
    const float* __restrict__ Wd, float* __restrict__ ws)
{
  const int which = blockIdx.y;  // 0=AF 1=WdT 2=WT transpose+split
  const int tid = threadIdx.x;
  __shared__ __align__(16) float a_s[8][256];
  if (which == 0) {
    // pack bf16(Hq) into MFMA A-fragment order:
    // AF[((((b*4+w)*4+mt)*8+kt)*64 + quad*16 + c16)*8 + j]
    const int m0 = blockIdx.x * 8;
    unsigned short* AF = (unsigned short*)((char*)ws + 3145728);
    const int row = m0 + (tid >> 5);
    const int grp = tid & 31;
    const int kt = grp >> 2, quad = grp & 3;
    const int k0 = kt * 32 + quad * 8;
    const int bb = row >> 8, q = row & 255;
    const int w = q >> 6, mt = (q >> 4) & 3, c16 = q & 15;
    const float* src = Hq + row * ND + k0;
    f32x4 v0 = *(const f32x4*)(src);
    f32x4 v1 = *(const f32x4*)(src + 4);
    s16x8 o;
    #pragma unroll
    for (int j = 0; j < 4; ++j) { o[j] = (short)f2b(v0[j]); o[4 + j] = (short)f2b(v1[j]); }
    *(s16x8*)(AF + ((((bb * 4 + w) * 4 + mt) * 8 + kt) * 64 + quad * 16 + c16) * 8) = o;
    return;
  }
  if (which == 1) {
    // transpose Wd -> WdT[h][k] fp32 (prescaled by TANH_S) via LDS
    if (blockIdx.x >= 32) return;
    const int k0 = blockIdx.x * 8;
    #pragma unroll
    for (int kk = 0; kk < 8; ++kk)
      a_s[kk][tid] = Wd[(k0 + kk) * NH + tid] * TANH_S;
    __syncthreads();
    float* WdT = (float*)((char*)ws + 5767168);
    f32x4 v0 = {a_s[0][tid], a_s[1][tid], a_s[2][tid], a_s[3][tid]};
    f32x4 v1 = {a_s[4][tid], a_s[5][tid], a_s[6][tid], a_s[7][tid]};
    *(f32x4*)(WdT + tid * 256 + k0) = v0;
    *(f32x4*)(WdT + tid * 256 + k0 + 4) = v1;
    return;
  }
  // which == 2: transpose + bf16-split the 4 score weights
  const int w = blockIdx.x >> 5;          // 0..3
  const int k0 = (blockIdx.x & 31) * 8;
  const float* W = (w == 0) ? Wc1 : (w == 1) ? Wm : (w == 2) ? Wb : Wc2;
  const float scale = (w == 2) ? 1.0f : TANH_S;
  #pragma unroll
  for (int kk = 0; kk < 8; ++kk)
    a_s[kk][tid] = W[(k0 + kk) * NH + tid] * scale;
  __syncthreads();
  unsigned short* WT = (unsigned short*)((char*)ws + 4718592) + w * 131072;
  s16x8 hi, lo;
  #pragma unroll
  for (int kk = 0; kk < 8; ++kk) {
    float v = a_s[kk][tid];
    unsigned short h = f2b(v);
    hi[kk] = (short)h;
    lo[kk] = (short)f2b(v - b2f(h));
  }
  *(s16x8*)(WT + tid * 256 + k0) = hi;
  *(s16x8*)(WT + 65536 + tid * 256 + k0) = lo;
}

// ---- all 5 prep GEMMs via split-bf16 MFMA, LDS-staged weights.
// grid (16 rowtiles, 8 coltiles, 5 matrices) = 640 blocks; tile 64 rows x 32 cols.
// z: 0=EC1(Hq,w0,exp2,bf16) 1=EM1(Hq,w1,exp2,bf16) 2=X(Hq,w2) 3=C2b(Hp,w3) 4=M2b(Hp,w1)
__global__ void __launch_bounds__(256) gemm5(
    const float* __restrict__ Hq, const float* __restrict__ Hp,
    float* __restrict__ ws)
{
  const int rt = blockIdx.x, ct = blockIdx.y, mz = blockIdx.z;
  const int tid = threadIdx.x;
  const int wave = tid >> 6, lane = tid & 63;
  const int quad = lane >> 4, c16 = lane & 15;

  __shared__ __align__(16) char bs[32768];  // BsH 16K | BsL 16K
  char* BsH = bs;
  char* BsL = bs + 16384;

  const int w = (mz == 4) ? 1 : ((mz == 3) ? 3 : mz);
  const float* A = (mz >= 3) ? Hp : Hq;
  const int n0 = ct * 32;

  { // stage WH/WL rows [n0, n0+32) x k[0,256) into LDS with XOR swizzle
    const unsigned short* WTw = (const unsigned short*)((const char*)ws + 4718592)
                                + w * 131072 + n0 * 256;
    const int soff = (tid & 31) * 16;
    #pragma unroll
    for (int i = 0; i < 4; ++i) {
      const int h = i * 8 + (tid >> 5);
      const int doff = h * 512 + (soff ^ ((h & 7) * 16));
      u32x4 vh = *(const u32x4*)((const char*)WTw + h * 512 + soff);
      u32x4 vl = *(const u32x4*)((const char*)WTw + 131072 + h * 512 + soff);
      *(u32x4*)(BsH + doff) = vh;
      *(u32x4*)(BsL + doff) = vl;
    }
  }

  // A fragments: row = rt*64 + wave*16 + c16, split hi/lo
  const int row = rt * 64 + wave * 16 + c16;
  s16x8 ah[8], al[8];
  #pragma unroll
  for (int kt = 0; kt < 8; ++kt) {
    const float* src = A + row * ND + kt * 32 + quad * 8;
    f32x4 v0 = *(const f32x4*)(src);
    f32x4 v1 = *(const f32x4*)(src + 4);
    #pragma unroll
    for (int j = 0; j < 4; ++j) {
      unsigned short h0 = f2b(v0[j]);
      ah[kt][j] = (short)h0;
      al[kt][j] = (short)f2b(v0[j] - b2f(h0));
      unsigned short h1 = f2b(v1[j]);
      ah[kt][4 + j] = (short)h1;
      al[kt][4 + j] = (short)f2b(v1[j] - b2f(h1));
    }
  }
  __syncthreads();

  f32x4 acc[2];
  #pragma unroll
  for (int nt = 0; nt < 2; ++nt) acc[nt] = f32x4{0.f, 0.f, 0.f, 0.f};

  const int xswz = (c16 & 7) * 16;
  #pragma unroll
  for (int kt = 0; kt < 8; ++kt) {
    #pragma unroll
    for (int nt = 0; nt < 2; ++nt) {
      const int baddr = (nt * 16 + c16) * 512 + ((kt * 64 + quad * 16) ^ xswz);
      s16x8 bh = *(const s16x8*)(BsH + baddr);
      s16x8 bl = *(const s16x8*)(BsL + baddr);
      acc[nt] = __builtin_amdgcn_mfma_f32_16x16x32_bf16(ah[kt], bh, acc[nt], 0, 0, 0);
      acc[nt] = __builtin_amdgcn_mfma_f32_16x16x32_bf16(al[kt], bh, acc[nt], 0, 0, 0);
      acc[nt] = __builtin_amdgcn_mfma_f32_16x16x32_bf16(ah[kt], bl, acc[nt], 0, 0, 0);
    }
  }

  const int orow0 = rt * 64 + wave * 16 + quad * 4;
  if (mz == 2) {  // X fp32
    #pragma unroll
    for (int nt = 0; nt < 2; ++nt)
      #pragma unroll
      for (int r = 0; r < 4; ++r)
        ws[(orow0 + r) * NH + n0 + nt * 16 + c16] = acc[nt][r];
  } else if (mz < 2) {  // EC1 / EM1: bf16(exp2(scaled score part))
    unsigned short* E = (unsigned short*)((char*)ws +
        (mz == 0 ? 1048576 : 1572864));
    #pragma unroll
    for (int nt = 0; nt < 2; ++nt)
      #pragma unroll
      for (int r = 0; r < 4; ++r)
        E[(orow0 + r) * NH + n0 + nt * 16 + c16] =
            f2b(__builtin_amdgcn_exp2f(acc[nt][r]));
  } else {  // C2b / M2b bf16
    unsigned short* O = (unsigned short*)((char*)ws +
        (mz == 3 ? 3670016 : 4194304));
    #pragma unroll
    for (int nt = 0; nt < 2; ++nt)
      #pragma unroll
      for (int r = 0; r < 4; ++r)
        O[(orow0 + r) * NH + n0 + nt * 16 + c16] = f2b(acc[nt][r]);
  }
}

// ---- merged: branch-d MFMA GEMM + tanh reduce, then scores c/b/m,
// softmax(all 4), attend(all 4). One block per (b,p); d-scores stay in LDS.
// R14 config: __launch_bounds__(256,4) -> 64-VGPR/8-wave regime. Measured
// frontier: 64reg+spill/8w = 100us < 112reg/4w = 139us < 132reg/3w = 170us.
__global__ void __launch_bounds__(256, 4) dfused(
    const float* __restrict__ Hp, const float* __restrict__ Hq,
    const float* __restrict__ vd, const float* __restrict__ vc,
    const float* __restrict__ vm, const float* __restrict__ ws,
    float* __restrict__ out)
{
  const int p = blockIdx.x, b = blockIdx.y;
  const int tid = threadIdx.x;
  const int wave = tid >> 6, lane = tid & 63;
  const int quad = lane >> 4, c16 = lane & 15;

  __shared__ __align__(16) char ovl[33792];
  __shared__ __align__(16) float sc4[4 * 256];  // rows: 0=c 1=b 2=d 3=m
  __shared__ __align__(16) float hp_s[256];
  __shared__ __align__(16) float invsum[4];

  short* Bs = (short*)ovl;                       // 32 KB, dphase
  float* vd2_s = (float*)(ovl + 32768);          // 1 KB, dphase
  float* redp = (float*)ovl;                     // 16 KB, fphase
  float* e2c_s = (float*)(ovl + 16384);          // fphase: exp2(c2s)
  float* e2m_s = (float*)(ovl + 17408);          // fphase: exp2(-m2s)
  float* vc2_s = (float*)(ovl + 18432);
  float* vm2_s = (float*)(ovl + 19456);

  const unsigned short* AF = (const unsigned short*)((const char*)ws + 3145728);
  const float* WdT = (const float*)((const char*)ws + 5767168);
  const float* X = ws;
  const unsigned short* EC1 = (const unsigned short*)((const char*)ws + 1048576);
  const unsigned short* EM1 = (const unsigned short*)((const char*)ws + 1572864);
  const unsigned short* C2b = (const unsigned short*)((const char*)ws + 3670016);
  const unsigned short* M2b = (const unsigned short*)((const char*)ws + 4194304);

  hp_s[tid] = Hp[(b * NL + p) * ND + tid];
  vd2_s[tid] = 2.0f * vd[tid];
  __syncthreads();

  // ======== phase 1: branch d ====
  {
    const int scol = (tid & 63) * 4;
    const f32x4 hpv = *(const f32x4*)(hp_s + scol);
    const int wq0 = wave * 64;
    const unsigned short* AFw = AF + (b * 4 + wave) * 4 * 8 * 64 * 8;
    const int xswz = (c16 & 7) * 16;

    float sdp[4][4];
    #pragma unroll
    for (int mt = 0; mt < 4; ++mt)
      #pragma unroll
      for (int r = 0; r < 4; ++r) sdp[mt][r] = 0.f;
    float vs2 = 0.f;

    for (int ht = 0; ht < 4; ++ht) {
      const int h0 = ht * 64;
      __syncthreads();
      { // stage Bs[h][k] = bf16(WdT[h0+h][k]*hp[k]); coalesced 1KB/wave
        const float* wsrc = WdT + h0 * 256 + tid * 4;
        #pragma unroll
        for (int i = 0; i < 16; ++i) {
          f32x4 wv = *(const f32x4*)(wsrc + i * 1024);
          const int h = i * 4 + (tid >> 6);
          const unsigned int u0 = cvtpk(wv[0] * hpv[0], wv[1] * hpv[1]);
          const unsigned int u1 = cvtpk(wv[2] * hpv[2], wv[3] * hpv[3]);
          const int baddr = h * 512 + (((tid & 63) * 8) ^ ((h & 7) * 16));
          *(u32x2*)((char*)Bs + baddr) = u32x2{u0, u1};
        }
      }
      __syncthreads();

      f32x4 acc[4][4];
      #pragma unroll
      for (int mt = 0; mt < 4; ++mt)
        #pragma unroll
        for (int nt = 0; nt < 4; ++nt) acc[mt][nt] = f32x4{0.f, 0.f, 0.f, 0.f};

      #pragma unroll 2
      for (int kt = 0; kt < 8; ++kt) {
        s16x8 a8[4];
        #pragma unroll
        for (int mt = 0; mt < 4; ++mt)
          a8[mt] = *(const s16x8*)(AFw + ((mt * 8 + kt) * 64 + lane) * 8);
        #pragma unroll
        for (int nt = 0; nt < 4; ++nt) {
          const int baddr = (nt * 16 + c16) * 512 + ((kt * 64 + quad * 16) ^ xswz);
          s16x8 b8 = *(const s16x8*)((const char*)Bs + baddr);
          #pragma unroll
          for (int mt = 0; mt < 4; ++mt)
            acc[mt][nt] = __builtin_amdgcn_mfma_f32_16x16x32_bf16(
                a8[mt], b8, acc[mt][nt], 0, 0, 0);
        }
      }

      // vd*tanh(z) = vd - vd2*rcp(e^{2z}+1); acc already 2*log2e*z
      #pragma unroll
      for (int nt = 0; nt < 4; ++nt) {
        const float v2 = vd2_s[h0 + nt * 16 + c16];
        vs2 += v2;
        #pragma unroll
        for (int mt = 0; mt < 4; ++mt) {
          #pragma unroll
          for (int r = 0; r < 4; ++r) {
            float e = __builtin_amdgcn_exp2f(acc[mt][nt][r]);
            sdp[mt][r] += v2 * __builtin_amdgcn_rcpf(e + 1.0f);
          }
        }
      }
    }

    // deferred 16-lane reduce -> d-scores into sc4[512+q]
    #pragma unroll
    for (int m = 1; m < 16; m <<= 1) vs2 += __shfl_xor(vs2, m, 64);
    #pragma unroll
    for (int mt = 0; mt < 4; ++mt)
      #pragma unroll
      for (int r = 0; r < 4; ++r) {
        float v = sdp[mt][r];
        #pragma unroll
        for (int m = 1; m < 16; m <<= 1) v += __shfl_xor(v, m, 64);
        if (c16 == 0)
          sc4[512 + wq0 + mt * 16 + quad * 4 + r] = 0.5f * vs2 - v;
      }
  }
  __syncthreads();  // Bs dead; overlay becomes fphase arrays

  { // fphase LDS loads; one exp2 per thread folds c2/m2 into multipliers
    const int r = (b * NL + p) * ND + tid;
    e2c_s[tid] = __builtin_amdgcn_exp2f(b2f(C2b[r]));
    e2m_s[tid] = __builtin_amdgcn_exp2f(-b2f(M2b[r]));
    vc2_s[tid] = 2.0f * vc[tid];
    vm2_s[tid] = 2.0f * vm[tid];
  }
  __syncthreads();

  // ======== phase 2: scores c, b, m (no exp2 in inner loop; bf16 EC1/EM1) =
  {
    const int qsub = lane >> 4;
    const int hb = c16 * 4;
    float lc = 0.f, lm = 0.f;
    #pragma unroll
    for (int hi = 0; hi < 4; ++hi) {
      const int h = hb + hi * 64;
      #pragma unroll
      for (int i = 0; i < 4; ++i) { lc += vc2_s[h + i]; lm += vm2_s[h + i]; }
    }
    #pragma unroll
    for (int m = 1; m < 16; m <<= 1) {
      lc += __shfl_xor(lc, m, 64);
      lm += __shfl_xor(lm, m, 64);
    }
    const float c0 = 0.5f * lc, m0 = 0.5f * lm;

    for (int qg = 0; qg < 16; ++qg) {
      const int q = wave * 64 + qg * 4 + qsub;
      const unsigned short* ecr = EC1 + (b * NL + q) * NH;
      const unsigned short* emr = EM1 + (b * NL + q) * NH;
      const float* xr  = X + (b * NL + q) * ND;
      float pcr0 = 0.f, pmr0 = 0.f, pb0 = 0.f;
      float pcr1 = 0.f, pmr1 = 0.f, pb1 = 0.f;
      #pragma unroll
      for (int hi = 0; hi < 4; ++hi) {
        const int h = hb + hi * 64;
        s16x4 ec = *(const s16x4*)(ecr + h);
        s16x4 em = *(const s16x4*)(emr + h);
        f32x4 xv = *(const f32x4*)(xr + h);
        #pragma unroll
        for (int i = 0; i < 4; ++i) {
          float tc = b2f((unsigned short)ec[i]) * e2c_s[h + i] + 1.0f;
          float tm = b2f((unsigned short)em[i]) * e2m_s[h + i] + 1.0f;
          if (i & 1) {
            pcr1 += vc2_s[h + i] * __builtin_amdgcn_rcpf(tc);
            pmr1 += vm2_s[h + i] * __builtin_amdgcn_rcpf(tm);
            pb1 += hp_s[h + i] * xv[i];
          } else {
            pcr0 += vc2_s[h + i] * __builtin_amdgcn_rcpf(tc);
            pmr0 += vm2_s[h + i] * __builtin_amdgcn_rcpf(tm);
            pb0 += hp_s[h + i] * xv[i];
          }
        }
      }
      float pcr = pcr0 + pcr1, pmr = pmr0 + pmr1, pb = pb0 + pb1;
      #pragma unroll
      for (int m = 1; m < 16; m <<= 1) {
        pcr += __shfl_xor(pcr, m, 64);
        pmr += __shfl_xor(pmr, m, 64);
        pb  += __shfl_xor(pb, m, 64);
      }
      if (c16 == 0) {
        sc4[q]       = c0 - pcr;
        sc4[256 + q] = pb;
        sc4[768 + q] = m0 - pmr;
      }
    }
  }
  __syncthreads();

  // ======== phase 3: softmax; wave w owns branch w ======================
  {
    float s0 = sc4[wave * 256 + lane];
    float s1 = sc4[wave * 256 + lane + 64];
    float s2 = sc4[wave * 256 + lane + 128];
    float s3 = sc4[wave * 256 + lane + 192];
    float mx = fmaxf(fmaxf(s0, s1), fmaxf(s2, s3));
    #pragma unroll
    for (int m = 1; m < 64; m <<= 1) mx = fmaxf(mx, __shfl_xor(mx, m, 64));
    float e0 = __builtin_amdgcn_exp2f((s0 - mx) * LOG2E);
    float e1 = __builtin_amdgcn_exp2f((s1 - mx) * LOG2E);
    float e2 = __builtin_amdgcn_exp2f((s2 - mx) * LOG2E);
    float e3 = __builtin_amdgcn_exp2f((s3 - mx) * LOG2E);
    float sm = e0 + e1 + e2 + e3;
    #pragma unroll
    for (int m = 1; m < 64; m <<= 1) sm += __shfl_xor(sm, m, 64);
    sc4[wave * 256 + lane]       = e0;
    sc4[wave * 256 + lane + 64]  = e1;
    sc4[wave * 256 + lane + 128] = e2;
    sc4[wave * 256 + lane + 192] = e3;
    if (lane == 0) invsum[wave] = __builtin_amdgcn_rcpf(sm);
  }
  __syncthreads();

  // ======== phase 4: attend =============================================
  {
    const int q0 = wave * 64;
    f32x4 pa0 = {0.f,0.f,0.f,0.f}, pa1 = {0.f,0.f,0.f,0.f};
    f32x4 pa2 = {0.f,0.f,0.f,0.f}, pa3 = {0.f,0.f,0.f,0.f};
    for (int qi = 0; qi < 64; ++qi) {
      const int q = q0 + qi;
      const float ac = sc4[q];
      const float ab = sc4[256 + q];
      const float ad = sc4[512 + q];
      const float am = sc4[768 + q];
      f32x4 hv = *(const f32x4*)(Hq + (b * NL + q) * ND + lane * 4);
      pa0 += ac * hv; pa1 += ab * hv; pa2 += ad * hv; pa3 += am * hv;
    }
    *(f32x4*)(redp + (wave * 4 + 0) * 256 + lane * 4) = pa0;
    *(f32x4*)(redp + (wave * 4 + 1) * 256 + lane * 4) = pa1;
    *(f32x4*)(redp + (wave * 4 + 2) * 256 + lane * 4) = pa2;
    *(f32x4*)(redp + (wave * 4 + 3) * 256 + lane * 4) = pa3;
  }
  __syncthreads();

  // ======== phase 5: cross-wave reduce + normalize + store ==============
  {
    #pragma unroll
    for (int br = 0; br < 4; ++br) {
      float s = redp[(0 * 4 + br) * 256 + tid] + redp[(1 * 4 + br) * 256 + tid]
              + redp[(2 * 4 + br) * 256 + tid] + redp[(3 * 4 + br) * 256 + tid];
      out[((br * NB + b) * NL + p) * ND + tid] = s * invsum[br];
    }
  }
}

extern "C" void kernel_launch(void* const* d_in, const int* in_sizes, int n_in,
                              void* d_out, int out_size, void* d_ws, size_t ws_size,
                              hipStream_t stream) {
  const float* Hp  = (const float*)d_in[0];
  const float* Hq  = (const float*)d_in[1];
  const float* Wc1 = (const float*)d_in[2];
  const float* Wc2 = (const float*)d_in[3];
  const float* vc  = (const float*)d_in[4];
  const float* Wb  = (const float*)d_in[5];
  const float* Wd  = (const float*)d_in[6];
  const float* vd  = (const float*)d_in[7];
  const float* Wm  = (const float*)d_in[8];
  const float* vm  = (const float*)d_in[9];
  float* ws = (float*)d_ws;
  float* out = (float*)d_out;

  hipLaunchKernelGGL(prep, dim3(128, 3), dim3(256), 0, stream,
                     Hq, Wc1, Wc2, Wb, Wm, Wd, ws);
  hipLaunchKernelGGL(gemm5, dim3(16, 8, 5), dim3(256), 0, stream,
                     Hq, Hp, ws);
  hipLaunchKernelGGL(dfused, dim3(256, 4), dim3(256), 0, stream,
                     Hp, Hq, vd, vc, vm, ws, out);
}

// Round 20
// 174.666 us; speedup vs baseline: 1.1779x; 1.0423x over previous
//
#include <hip/hip_runtime.h>

#define LOG2E 1.4426950408889634f
#define TANH_S 2.8853900817779268f  // 2*log2(e)
#define NB 4
#define NL 256
#define ND 256
#define NH 256

typedef __attribute__((ext_vector_type(8))) short s16x8;
typedef __attribute__((ext_vector_type(4))) short s16x4;
typedef __attribute__((ext_vector_type(4))) float f32x4;
typedef __attribute__((ext_vector_type(2))) unsigned int u32x2;
typedef __attribute__((ext_vector_type(4))) unsigned int u32x4;

static __device__ __forceinline__ float b2f(unsigned short u) {
  return __builtin_bit_cast(float, (unsigned int)u << 16);
}
static __device__ __forceinline__ unsigned short f2b(float f) {
  unsigned int x = __builtin_bit_cast(unsigned int, f);
  return (unsigned short)((x + 0x7fffu + ((x >> 16) & 1u)) >> 16);
}
static __device__ __forceinline__ unsigned int cvtpk(float lo, float hi) {
  unsigned int r;
  asm("v_cvt_pk_bf16_f32 %0, %1, %2" : "=v"(r) : "v"(lo), "v"(hi));
  return r;
}

// ws layout (5.75 MB):
//   X    fp32 [0,      1M)    : Hq@Wb
//   EC1  fp32 [1M,     2M)    : exp2(TANH_S*(Hq@Wc1))
//   EM1  fp32 [2M,     3M)    : exp2(TANH_S*(Hq@Wm))
//   AF   bf16 [3M,   3.5M)    : Hq packed in MFMA A-fragment order
//   C2b  bf16 [3.5M,   4M)    : (Hp@Wc2)*TANH_S
//   M2b  bf16 [4M,   4.5M)    : (Hp@Wm)*TANH_S
//   WT   bf16 [4.5M, 5.5M)    : 4x transposed+split weights [n][k]:
//                               w=0 Wc1*S, 1 Wm*S, 2 Wb, 3 Wc2*S (hi+lo 128K each)
//   WdT  fp32 [5.5M, 5.75M)   : (Wd^T)*TANH_S  [h][k] (256 KB)

__global__ void __launch_bounds__(256) prep(
    const float* __restrict__ Hq,
    const float* __restrict__ Wc1, const float* __restrict__ Wc2,
    const float* __restrict__ Wb, const float* __restrict__ Wm,
    const float* __restrict__ Wd, float* __restrict__ ws)
{
  const int which = blockIdx.y;  // 0=AF 1=WdT 2=WT transpose+split
  const int tid = threadIdx.x;
  __shared__ __align__(16) float a_s[8][256];
  if (which == 0) {
    // pack bf16(Hq) into MFMA A-fragment order:
    // AF[((((b*4+w)*4+mt)*8+kt)*64 + quad*16 + c16)*8 + j]
    const int m0 = blockIdx.x * 8;
    unsigned short* AF = (unsigned short*)((char*)ws + 3145728);
    const int row = m0 + (tid >> 5);
    const int grp = tid & 31;
    const int kt = grp >> 2, quad = grp & 3;
    const int k0 = kt * 32 + quad * 8;
    const int bb = row >> 8, q = row & 255;
    const int w = q >> 6, mt = (q >> 4) & 3, c16 = q & 15;
    const float* src = Hq + row * ND + k0;
    f32x4 v0 = *(const f32x4*)(src);
    f32x4 v1 = *(const f32x4*)(src + 4);
    s16x8 o;
    #pragma unroll
    for (int j = 0; j < 4; ++j) { o[j] = (short)f2b(v0[j]); o[4 + j] = (short)f2b(v1[j]); }
    *(s16x8*)(AF + ((((bb * 4 + w) * 4 + mt) * 8 + kt) * 64 + quad * 16 + c16) * 8) = o;
    return;
  }
  if (which == 1) {
    // transpose Wd -> WdT[h][k] fp32 (prescaled by TANH_S) via LDS
    if (blockIdx.x >= 32) return;
    const int k0 = blockIdx.x * 8;
    #pragma unroll
    for (int kk = 0; kk < 8; ++kk)
      a_s[kk][tid] = Wd[(k0 + kk) * NH + tid] * TANH_S;
    __syncthreads();
    float* WdT = (float*)((char*)ws + 5767168);
    f32x4 v0 = {a_s[0][tid], a_s[1][tid], a_s[2][tid], a_s[3][tid]};
    f32x4 v1 = {a_s[4][tid], a_s[5][tid], a_s[6][tid], a_s[7][tid]};
    *(f32x4*)(WdT + tid * 256 + k0) = v0;
    *(f32x4*)(WdT + tid * 256 + k0 + 4) = v1;
    return;
  }
  // which == 2: transpose + bf16-split the 4 score weights
  const int w = blockIdx.x >> 5;          // 0..3
  const int k0 = (blockIdx.x & 31) * 8;
  const float* W = (w == 0) ? Wc1 : (w == 1) ? Wm : (w == 2) ? Wb : Wc2;
  const float scale = (w == 2) ? 1.0f : TANH_S;
  #pragma unroll
  for (int kk = 0; kk < 8; ++kk)
    a_s[kk][tid] = W[(k0 + kk) * NH + tid] * scale;
  __syncthreads();
  unsigned short* WT = (unsigned short*)((char*)ws + 4718592) + w * 131072;
  s16x8 hi, lo;
  #pragma unroll
  for (int kk = 0; kk < 8; ++kk) {
    float v = a_s[kk][tid];
    unsigned short h = f2b(v);
    hi[kk] = (short)h;
    lo[kk] = (short)f2b(v - b2f(h));
  }
  *(s16x8*)(WT + tid * 256 + k0) = hi;
  *(s16x8*)(WT + 65536 + tid * 256 + k0) = lo;
}

// ---- all 5 prep GEMMs via split-bf16 MFMA, LDS-staged weights.
// grid (16 rowtiles, 8 coltiles, 5 matrices) = 640 blocks; tile 64 rows x 32 cols.
// z: 0=EC1(Hq,w0,exp2) 1=EM1(Hq,w1,exp2) 2=X(Hq,w2) 3=C2b(Hp,w3) 4=M2b(Hp,w1)
__global__ void __launch_bounds__(256) gemm5(
    const float* __restrict__ Hq, const float* __restrict__ Hp,
    float* __restrict__ ws)
{
  const int rt = blockIdx.x, ct = blockIdx.y, mz = blockIdx.z;
  const int tid = threadIdx.x;
  const int wave = tid >> 6, lane = tid & 63;
  const int quad = lane >> 4, c16 = lane & 15;

  __shared__ __align__(16) char bs[32768];  // BsH 16K | BsL 16K
  char* BsH = bs;
  char* BsL = bs + 16384;

  const int w = (mz == 4) ? 1 : ((mz == 3) ? 3 : mz);
  const float* A = (mz >= 3) ? Hp : Hq;
  const int n0 = ct * 32;

  { // stage WH/WL rows [n0, n0+32) x k[0,256) into LDS with XOR swizzle
    const unsigned short* WTw = (const unsigned short*)((const char*)ws + 4718592)
                                + w * 131072 + n0 * 256;
    const int soff = (tid & 31) * 16;
    #pragma unroll
    for (int i = 0; i < 4; ++i) {
      const int h = i * 8 + (tid >> 5);
      const int doff = h * 512 + (soff ^ ((h & 7) * 16));
      u32x4 vh = *(const u32x4*)((const char*)WTw + h * 512 + soff);
      u32x4 vl = *(const u32x4*)((const char*)WTw + 131072 + h * 512 + soff);
      *(u32x4*)(BsH + doff) = vh;
      *(u32x4*)(BsL + doff) = vl;
    }
  }

  // A fragments: row = rt*64 + wave*16 + c16, split hi/lo
  const int row = rt * 64 + wave * 16 + c16;
  s16x8 ah[8], al[8];
  #pragma unroll
  for (int kt = 0; kt < 8; ++kt) {
    const float* src = A + row * ND + kt * 32 + quad * 8;
    f32x4 v0 = *(const f32x4*)(src);
    f32x4 v1 = *(const f32x4*)(src + 4);
    #pragma unroll
    for (int j = 0; j < 4; ++j) {
      unsigned short h0 = f2b(v0[j]);
      ah[kt][j] = (short)h0;
      al[kt][j] = (short)f2b(v0[j] - b2f(h0));
      unsigned short h1 = f2b(v1[j]);
      ah[kt][4 + j] = (short)h1;
      al[kt][4 + j] = (short)f2b(v1[j] - b2f(h1));
    }
  }
  __syncthreads();

  f32x4 acc[2];
  #pragma unroll
  for (int nt = 0; nt < 2; ++nt) acc[nt] = f32x4{0.f, 0.f, 0.f, 0.f};

  const int xswz = (c16 & 7) * 16;
  #pragma unroll
  for (int kt = 0; kt < 8; ++kt) {
    #pragma unroll
    for (int nt = 0; nt < 2; ++nt) {
      const int baddr = (nt * 16 + c16) * 512 + ((kt * 64 + quad * 16) ^ xswz);
      s16x8 bh = *(const s16x8*)(BsH + baddr);
      s16x8 bl = *(const s16x8*)(BsL + baddr);
      acc[nt] = __builtin_amdgcn_mfma_f32_16x16x32_bf16(ah[kt], bh, acc[nt], 0, 0, 0);
      acc[nt] = __builtin_amdgcn_mfma_f32_16x16x32_bf16(al[kt], bh, acc[nt], 0, 0, 0);
      acc[nt] = __builtin_amdgcn_mfma_f32_16x16x32_bf16(ah[kt], bl, acc[nt], 0, 0, 0);
    }
  }

  const int orow0 = rt * 64 + wave * 16 + quad * 4;
  if (mz == 2) {  // X fp32
    #pragma unroll
    for (int nt = 0; nt < 2; ++nt)
      #pragma unroll
      for (int r = 0; r < 4; ++r)
        ws[(orow0 + r) * NH + n0 + nt * 16 + c16] = acc[nt][r];
  } else if (mz < 2) {  // EC1 / EM1: store exp2 of scaled score part, fp32
    float* E = (float*)((char*)ws + (mz == 0 ? 1048576 : 2097152));
    #pragma unroll
    for (int nt = 0; nt < 2; ++nt)
      #pragma unroll
      for (int r = 0; r < 4; ++r)
        E[(orow0 + r) * NH + n0 + nt * 16 + c16] =
            __builtin_amdgcn_exp2f(acc[nt][r]);
  } else {  // C2b / M2b bf16
    unsigned short* O = (unsigned short*)((char*)ws +
        (mz == 3 ? 3670016 : 4194304));
    #pragma unroll
    for (int nt = 0; nt < 2; ++nt)
      #pragma unroll
      for (int r = 0; r < 4; ++r)
        O[(orow0 + r) * NH + n0 + nt * 16 + c16] = f2b(acc[nt][r]);
  }
}

// ---- merged: branch-d MFMA GEMM + tanh reduce, then scores c/b/m,
// softmax(all 4), attend(all 4). One block per (b,p); d-scores stay in LDS.
// Config: __launch_bounds__(256,4) -> 64-VGPR/8-wave regime — measured best
// on the frontier {64r+spill/8w: 100us} < {112r/4w: 139} < {132r/3w: 170}.
__global__ void __launch_bounds__(256, 4) dfused(
    const float* __restrict__ Hp, const float* __restrict__ Hq,
    const float* __restrict__ vd, const float* __restrict__ vc,
    const float* __restrict__ vm, const float* __restrict__ ws,
    float* __restrict__ out)
{
  const int p = blockIdx.x, b = blockIdx.y;
  const int tid = threadIdx.x;
  const int wave = tid >> 6, lane = tid & 63;
  const int quad = lane >> 4, c16 = lane & 15;

  __shared__ __align__(16) char ovl[33792];
  __shared__ __align__(16) float sc4[4 * 256];  // rows: 0=c 1=b 2=d 3=m
  __shared__ __align__(16) float hp_s[256];
  __shared__ __align__(16) float invsum[4];

  short* Bs = (short*)ovl;                       // 32 KB, dphase
  float* vd2_s = (float*)(ovl + 32768);          // 1 KB, dphase
  float* redp = (float*)ovl;                     // 16 KB, fphase
  float* e2c_s = (float*)(ovl + 16384);          // fphase: exp2(c2s)
  float* e2m_s = (float*)(ovl + 17408);          // fphase: exp2(-m2s)
  float* vc2_s = (float*)(ovl + 18432);
  float* vm2_s = (float*)(ovl + 19456);

  const unsigned short* AF = (const unsigned short*)((const char*)ws + 3145728);
  const float* WdT = (const float*)((const char*)ws + 5767168);
  const float* X = ws;
  const float* EC1 = (const float*)((const char*)ws + 1048576);
  const float* EM1 = (const float*)((const char*)ws + 2097152);
  const unsigned short* C2b = (const unsigned short*)((const char*)ws + 3670016);
  const unsigned short* M2b = (const unsigned short*)((const char*)ws + 4194304);

  hp_s[tid] = Hp[(b * NL + p) * ND + tid];
  vd2_s[tid] = 2.0f * vd[tid];
  __syncthreads();

  // ======== phase 1: branch d ====
  {
    const int scol = (tid & 63) * 4;
    const f32x4 hpv = *(const f32x4*)(hp_s + scol);
    const int wq0 = wave * 64;
    const unsigned short* AFw = AF + (b * 4 + wave) * 4 * 8 * 64 * 8;
    const int xswz = (c16 & 7) * 16;

    float sdp[4][4];
    #pragma unroll
    for (int mt = 0; mt < 4; ++mt)
      #pragma unroll
      for (int r = 0; r < 4; ++r) sdp[mt][r] = 0.f;
    float vs2 = 0.f;

    for (int ht = 0; ht < 4; ++ht) {
      const int h0 = ht * 64;
      __syncthreads();
      { // stage Bs[h][k] = bf16(WdT[h0+h][k]*hp[k]); coalesced 1KB/wave
        const float* wsrc = WdT + h0 * 256 + tid * 4;
        #pragma unroll
        for (int i = 0; i < 16; ++i) {
          f32x4 wv = *(const f32x4*)(wsrc + i * 1024);
          const int h = i * 4 + (tid >> 6);
          const unsigned int u0 = cvtpk(wv[0] * hpv[0], wv[1] * hpv[1]);
          const unsigned int u1 = cvtpk(wv[2] * hpv[2], wv[3] * hpv[3]);
          const int baddr = h * 512 + (((tid & 63) * 8) ^ ((h & 7) * 16));
          *(u32x2*)((char*)Bs + baddr) = u32x2{u0, u1};
        }
      }
      __syncthreads();

      f32x4 acc[4][4];
      #pragma unroll
      for (int mt = 0; mt < 4; ++mt)
        #pragma unroll
        for (int nt = 0; nt < 4; ++nt) acc[mt][nt] = f32x4{0.f, 0.f, 0.f, 0.f};

      #pragma unroll 2
      for (int kt = 0; kt < 8; ++kt) {
        s16x8 a8[4];
        #pragma unroll
        for (int mt = 0; mt < 4; ++mt)
          a8[mt] = *(const s16x8*)(AFw + ((mt * 8 + kt) * 64 + lane) * 8);
        #pragma unroll
        for (int nt = 0; nt < 4; ++nt) {
          const int baddr = (nt * 16 + c16) * 512 + ((kt * 64 + quad * 16) ^ xswz);
          s16x8 b8 = *(const s16x8*)((const char*)Bs + baddr);
          #pragma unroll
          for (int mt = 0; mt < 4; ++mt)
            acc[mt][nt] = __builtin_amdgcn_mfma_f32_16x16x32_bf16(
                a8[mt], b8, acc[mt][nt], 0, 0, 0);
        }
      }

      // vd*tanh(z) = vd - vd2*rcp(e^{2z}+1); acc already 2*log2e*z
      #pragma unroll
      for (int nt = 0; nt < 4; ++nt) {
        const float v2 = vd2_s[h0 + nt * 16 + c16];
        vs2 += v2;
        #pragma unroll
        for (int mt = 0; mt < 4; ++mt) {
          #pragma unroll
          for (int r = 0; r < 4; ++r) {
            float e = __builtin_amdgcn_exp2f(acc[mt][nt][r]);
            sdp[mt][r] += v2 * __builtin_amdgcn_rcpf(e + 1.0f);
          }
        }
      }
    }

    // deferred 16-lane reduce -> d-scores into sc4[512+q]
    #pragma unroll
    for (int m = 1; m < 16; m <<= 1) vs2 += __shfl_xor(vs2, m, 64);
    #pragma unroll
    for (int mt = 0; mt < 4; ++mt)
      #pragma unroll
      for (int r = 0; r < 4; ++r) {
        float v = sdp[mt][r];
        #pragma unroll
        for (int m = 1; m < 16; m <<= 1) v += __shfl_xor(v, m, 64);
        if (c16 == 0)
          sc4[512 + wq0 + mt * 16 + quad * 4 + r] = 0.5f * vs2 - v;
      }
  }
  __syncthreads();  // Bs dead; overlay becomes fphase arrays

  { // fphase LDS loads; one exp2 per thread folds c2/m2 into multipliers
    const int r = (b * NL + p) * ND + tid;
    e2c_s[tid] = __builtin_amdgcn_exp2f(b2f(C2b[r]));
    e2m_s[tid] = __builtin_amdgcn_exp2f(-b2f(M2b[r]));
    vc2_s[tid] = 2.0f * vc[tid];
    vm2_s[tid] = 2.0f * vm[tid];
  }
  __syncthreads();

  // ======== phase 2: scores c, b, m (no exp2 in inner loop) =============
  {
    const int qsub = lane >> 4;
    const int hb = c16 * 4;
    float lc = 0.f, lm = 0.f;
    #pragma unroll
    for (int hi = 0; hi < 4; ++hi) {
      const int h = hb + hi * 64;
      #pragma unroll
      for (int i = 0; i < 4; ++i) { lc += vc2_s[h + i]; lm += vm2_s[h + i]; }
    }
    #pragma unroll
    for (int m = 1; m < 16; m <<= 1) {
      lc += __shfl_xor(lc, m, 64);
      lm += __shfl_xor(lm, m, 64);
    }
    const float c0 = 0.5f * lc, m0 = 0.5f * lm;

    for (int qg = 0; qg < 16; ++qg) {
      const int q = wave * 64 + qg * 4 + qsub;
      const float* ecr = EC1 + (b * NL + q) * NH;
      const float* emr = EM1 + (b * NL + q) * NH;
      const float* xr  = X + (b * NL + q) * ND;
      float pcr0 = 0.f, pmr0 = 0.f, pb0 = 0.f;
      float pcr1 = 0.f, pmr1 = 0.f, pb1 = 0.f;
      #pragma unroll
      for (int hi = 0; hi < 4; ++hi) {
        const int h = hb + hi * 64;
        f32x4 ec = *(const f32x4*)(ecr + h);
        f32x4 em = *(const f32x4*)(emr + h);
        f32x4 xv = *(const f32x4*)(xr + h);
        #pragma unroll
        for (int i = 0; i < 4; ++i) {
          float tc = ec[i] * e2c_s[h + i] + 1.0f;
          float tm = em[i] * e2m_s[h + i] + 1.0f;
          if (i & 1) {
            pcr1 += vc2_s[h + i] * __builtin_amdgcn_rcpf(tc);
            pmr1 += vm2_s[h + i] * __builtin_amdgcn_rcpf(tm);
            pb1 += hp_s[h + i] * xv[i];
          } else {
            pcr0 += vc2_s[h + i] * __builtin_amdgcn_rcpf(tc);
            pmr0 += vm2_s[h + i] * __builtin_amdgcn_rcpf(tm);
            pb0 += hp_s[h + i] * xv[i];
          }
        }
      }
      float pcr = pcr0 + pcr1, pmr = pmr0 + pmr1, pb = pb0 + pb1;
      #pragma unroll
      for (int m = 1; m < 16; m <<= 1) {
        pcr += __shfl_xor(pcr, m, 64);
        pmr += __shfl_xor(pmr, m, 64);
        pb  += __shfl_xor(pb, m, 64);
      }
      if (c16 == 0) {
        sc4[q]       = c0 - pcr;
        sc4[256 + q] = pb;
        sc4[768 + q] = m0 - pmr;
      }
    }
  }
  __syncthreads();

  // ======== phase 3: softmax; wave w owns branch w ======================
  {
    float s0 = sc4[wave * 256 + lane];
    float s1 = sc4[wave * 256 + lane + 64];
    float s2 = sc4[wave * 256 + lane + 128];
    float s3 = sc4[wave * 256 + lane + 192];
    float mx = fmaxf(fmaxf(s0, s1), fmaxf(s2, s3));
    #pragma unroll
    for (int m = 1; m < 64; m <<= 1) mx = fmaxf(mx, __shfl_xor(mx, m, 64));
    float e0 = __builtin_amdgcn_exp2f((s0 - mx) * LOG2E);
    float e1 = __builtin_amdgcn_exp2f((s1 - mx) * LOG2E);
    float e2 = __builtin_amdgcn_exp2f((s2 - mx) * LOG2E);
    float e3 = __builtin_amdgcn_exp2f((s3 - mx) * LOG2E);
    float sm = e0 + e1 + e2 + e3;
    #pragma unroll
    for (int m = 1; m < 64; m <<= 1) sm += __shfl_xor(sm, m, 64);
    sc4[wave * 256 + lane]       = e0;
    sc4[wave * 256 + lane + 64]  = e1;
    sc4[wave * 256 + lane + 128] = e2;
    sc4[wave * 256 + lane + 192] = e3;
    if (lane == 0) invsum[wave] = __builtin_amdgcn_rcpf(sm);
  }
  __syncthreads();

  // ======== phase 4: attend =============================================
  {
    const int q0 = wave * 64;
    f32x4 pa0 = {0.f,0.f,0.f,0.f}, pa1 = {0.f,0.f,0.f,0.f};
    f32x4 pa2 = {0.f,0.f,0.f,0.f}, pa3 = {0.f,0.f,0.f,0.f};
    for (int qi = 0; qi < 64; ++qi) {
      const int q = q0 + qi;
      const float ac = sc4[q];
      const float ab = sc4[256 + q];
      const float ad = sc4[512 + q];
      const float am = sc4[768 + q];
      f32x4 hv = *(const f32x4*)(Hq + (b * NL + q) * ND + lane * 4);
      pa0 += ac * hv; pa1 += ab * hv; pa2 += ad * hv; pa3 += am * hv;
    }
    *(f32x4*)(redp + (wave * 4 + 0) * 256 + lane * 4) = pa0;
    *(f32x4*)(redp + (wave * 4 + 1) * 256 + lane * 4) = pa1;
    *(f32x4*)(redp + (wave * 4 + 2) * 256 + lane * 4) = pa2;
    *(f32x4*)(redp + (wave * 4 + 3) * 256 + lane * 4) = pa3;
  }
  __syncthreads();

  // ======== phase 5: cross-wave reduce + normalize + store ==============
  {
    #pragma unroll
    for (int br = 0; br < 4; ++br) {
      float s = redp[(0 * 4 + br) * 256 + tid] + redp[(1 * 4 + br) * 256 + tid]
              + redp[(2 * 4 + br) * 256 + tid] + redp[(3 * 4 + br) * 256 + tid];
      out[((br * NB + b) * NL + p) * ND + tid] = s * invsum[br];
    }
  }
}

extern "C" void kernel_launch(void* const* d_in, const int* in_sizes, int n_in,
                              void* d_out, int out_size, void* d_ws, size_t ws_size,
                              hipStream_t stream) {
  const float* Hp  = (const float*)d_in[0];
  const float* Hq  = (const float*)d_in[1];
  const float* Wc1 = (const float*)d_in[2];
  const float* Wc2 = (const float*)d_in[3];
  const float* vc  = (const float*)d_in[4];
  const float* Wb  = (const float*)d_in[5];
  const float* Wd  = (const float*)d_in[6];
  const float* vd  = (const float*)d_in[7];
  const float* Wm  = (const float*)d_in[8];
  const float* vm  = (const float*)d_in[9];
  float* ws = (float*)d_ws;
  float* out = (float*)d_out;

  hipLaunchKernelGGL(prep, dim3(128, 3), dim3(256), 0, stream,
                     Hq, Wc1, Wc2, Wb, Wm, Wd, ws);
  hipLaunchKernelGGL(gemm5, dim3(16, 8, 5), dim3(256), 0, stream,
                     Hq, Hp, ws);
  hipLaunchKernelGGL(dfused, dim3(256, 4), dim3(256), 0, stream,
                     Hp, Hq, vd, vc, vm, ws, out);
}

// Round 21
// 173.688 us; speedup vs baseline: 1.1845x; 1.0056x over previous
//
#include <hip/hip_runtime.h>

#define LOG2E 1.4426950408889634f
#define TANH_S 2.8853900817779268f  // 2*log2(e)
#define NB 4
#define NL 256
#define ND 256
#define NH 256

typedef __attribute__((ext_vector_type(8))) short s16x8;
typedef __attribute__((ext_vector_type(4))) short s16x4;
typedef __attribute__((ext_vector_type(4))) float f32x4;
typedef __attribute__((ext_vector_type(2))) unsigned int u32x2;
typedef __attribute__((ext_vector_type(4))) unsigned int u32x4;

static __device__ __forceinline__ float b2f(unsigned short u) {
  return __builtin_bit_cast(float, (unsigned int)u << 16);
}
static __device__ __forceinline__ unsigned short f2b(float f) {
  unsigned int x = __builtin_bit_cast(unsigned int, f);
  return (unsigned short)((x + 0x7fffu + ((x >> 16) & 1u)) >> 16);
}
static __device__ __forceinline__ unsigned int cvtpk(float lo, float hi) {
  unsigned int r;
  asm("v_cvt_pk_bf16_f32 %0, %1, %2" : "=v"(r) : "v"(lo), "v"(hi));
  return r;
}

// ws layout (5.75 MB):
//   X    fp32 [0,      1M)    : Hq@Wb
//   EC1  fp32 [1M,     2M)    : exp2(TANH_S*(Hq@Wc1))
//   EM1  fp32 [2M,     3M)    : exp2(TANH_S*(Hq@Wm))
//   AF   bf16 [3M,   3.5M)    : Hq packed in MFMA A-fragment order
//   C2b  bf16 [3.5M,   4M)    : (Hp@Wc2)*TANH_S
//   M2b  bf16 [4M,   4.5M)    : (Hp@Wm)*TANH_S
//   WT   bf16 [4.5M, 5.5M)    : 4x transposed+split weights [n][k]:
//                               w=0 Wc1*S, 1 Wm*S, 2 Wb, 3 Wc2*S (hi+lo 128K each)
//   WdT  fp32 [5.5M, 5.75M)   : (Wd^T)*TANH_S  [h][k] (256 KB)

__global__ void __launch_bounds__(256) prep(
    const float* __restrict__ Hq,
    const float* __restrict__ Wc1, const float* __restrict__ Wc2,
    const float* __restrict__ Wb, const float* __restrict__ Wm,
    const float* __restrict__ Wd, float* __restrict__ ws)
{
  const int which = blockIdx.y;  // 0=AF 1=WdT 2=WT transpose+split
  const int tid = threadIdx.x;
  __shared__ __align__(16) float a_s[8][256];
  if (which == 0) {
    // pack bf16(Hq) into MFMA A-fragment order:
    // AF[((((b*4+w)*4+mt)*8+kt)*64 + quad*16 + c16)*8 + j]
    const int m0 = blockIdx.x * 8;
    unsigned short* AF = (unsigned short*)((char*)ws + 3145728);
    const int row = m0 + (tid >> 5);
    const int grp = tid & 31;
    const int kt = grp >> 2, quad = grp & 3;
    const int k0 = kt * 32 + quad * 8;
    const int bb = row >> 8, q = row & 255;
    const int w = q >> 6, mt = (q >> 4) & 3, c16 = q & 15;
    const float* src = Hq + row * ND + k0;
    f32x4 v0 = *(const f32x4*)(src);
    f32x4 v1 = *(const f32x4*)(src + 4);
    s16x8 o;
    #pragma unroll
    for (int j = 0; j < 4; ++j) { o[j] = (short)f2b(v0[j]); o[4 + j] = (short)f2b(v1[j]); }
    *(s16x8*)(AF + ((((bb * 4 + w) * 4 + mt) * 8 + kt) * 64 + quad * 16 + c16) * 8) = o;
    return;
  }
  if (which == 1) {
    // transpose Wd -> WdT[h][k] fp32 (prescaled by TANH_S) via LDS
    if (blockIdx.x >= 32) return;
    const int k0 = blockIdx.x * 8;
    #pragma unroll
    for (int kk = 0; kk < 8; ++kk)
      a_s[kk][tid] = Wd[(k0 + kk) * NH + tid] * TANH_S;
    __syncthreads();
    float* WdT = (float*)((char*)ws + 5767168);
    f32x4 v0 = {a_s[0][tid], a_s[1][tid], a_s[2][tid], a_s[3][tid]};
    f32x4 v1 = {a_s[4][tid], a_s[5][tid], a_s[6][tid], a_s[7][tid]};
    *(f32x4*)(WdT + tid * 256 + k0) = v0;
    *(f32x4*)(WdT + tid * 256 + k0 + 4) = v1;
    return;
  }
  // which == 2: transpose + bf16-split the 4 score weights
  const int w = blockIdx.x >> 5;          // 0..3
  const int k0 = (blockIdx.x & 31) * 8;
  const float* W = (w == 0) ? Wc1 : (w == 1) ? Wm : (w == 2) ? Wb : Wc2;
  const float scale = (w == 2) ? 1.0f : TANH_S;
  #pragma unroll
  for (int kk = 0; kk < 8; ++kk)
    a_s[kk][tid] = W[(k0 + kk) * NH + tid] * scale;
  __syncthreads();
  unsigned short* WT = (unsigned short*)((char*)ws + 4718592) + w * 131072;
  s16x8 hi, lo;
  #pragma unroll
  for (int kk = 0; kk < 8; ++kk) {
    float v = a_s[kk][tid];
    unsigned short h = f2b(v);
    hi[kk] = (short)h;
    lo[kk] = (short)f2b(v - b2f(h));
  }
  *(s16x8*)(WT + tid * 256 + k0) = hi;
  *(s16x8*)(WT + 65536 + tid * 256 + k0) = lo;
}

// ---- all 5 prep GEMMs via MFMA, LDS-staged weights.
// grid (16 rowtiles, 8 coltiles, 5 matrices) = 640 blocks; tile 64 rows x 32 cols.
// z: 0=EC1(Hq,w0,exp2) 1=EM1(Hq,w1,exp2) 2=X(Hq,w2) 3=C2b(Hp,w3) 4=M2b(Hp,w1)
// v19: 3-MFMA compensated split ONLY for X (mz==2, raw softmax scores);
// tanh-arg streams (EC1/EM1/C2b/M2b) use plain bf16 (R0-class numerics) —
// 96 -> 32 MFMA and no residual build for 4 of 5 z-slices.
__global__ void __launch_bounds__(256) gemm5(
    const float* __restrict__ Hq, const float* __restrict__ Hp,
    float* __restrict__ ws)
{
  const int rt = blockIdx.x, ct = blockIdx.y, mz = blockIdx.z;
  const int tid = threadIdx.x;
  const int wave = tid >> 6, lane = tid & 63;
  const int quad = lane >> 4, c16 = lane & 15;

  __shared__ __align__(16) char bs[32768];  // BsH 16K | BsL 16K
  char* BsH = bs;
  char* BsL = bs + 16384;

  const int w = (mz == 4) ? 1 : ((mz == 3) ? 3 : mz);
  const float* A = (mz >= 3) ? Hp : Hq;
  const int n0 = ct * 32;
  const bool split = (mz == 2);

  { // stage WH (and WL if split) rows [n0,n0+32) x k[0,256), XOR swizzle
    const unsigned short* WTw = (const unsigned short*)((const char*)ws + 4718592)
                                + w * 131072 + n0 * 256;
    const int soff = (tid & 31) * 16;
    #pragma unroll
    for (int i = 0; i < 4; ++i) {
      const int h = i * 8 + (tid >> 5);
      const int doff = h * 512 + (soff ^ ((h & 7) * 16));
      u32x4 vh = *(const u32x4*)((const char*)WTw + h * 512 + soff);
      *(u32x4*)(BsH + doff) = vh;
      if (split) {
        u32x4 vl = *(const u32x4*)((const char*)WTw + 131072 + h * 512 + soff);
        *(u32x4*)(BsL + doff) = vl;
      }
    }
  }

  // A fragments: row = rt*64 + wave*16 + c16; hi always, lo only if split
  const int row = rt * 64 + wave * 16 + c16;
  s16x8 ah[8], al[8];
  #pragma unroll
  for (int kt = 0; kt < 8; ++kt) {
    const float* src = A + row * ND + kt * 32 + quad * 8;
    f32x4 v0 = *(const f32x4*)(src);
    f32x4 v1 = *(const f32x4*)(src + 4);
    #pragma unroll
    for (int j = 0; j < 4; ++j) {
      unsigned short h0 = f2b(v0[j]);
      ah[kt][j] = (short)h0;
      unsigned short h1 = f2b(v1[j]);
      ah[kt][4 + j] = (short)h1;
      if (split) {
        al[kt][j] = (short)f2b(v0[j] - b2f(h0));
        al[kt][4 + j] = (short)f2b(v1[j] - b2f(h1));
      }
    }
  }
  __syncthreads();

  f32x4 acc[2];
  #pragma unroll
  for (int nt = 0; nt < 2; ++nt) acc[nt] = f32x4{0.f, 0.f, 0.f, 0.f};

  const int xswz = (c16 & 7) * 16;
  #pragma unroll
  for (int kt = 0; kt < 8; ++kt) {
    #pragma unroll
    for (int nt = 0; nt < 2; ++nt) {
      const int baddr = (nt * 16 + c16) * 512 + ((kt * 64 + quad * 16) ^ xswz);
      s16x8 bh = *(const s16x8*)(BsH + baddr);
      acc[nt] = __builtin_amdgcn_mfma_f32_16x16x32_bf16(ah[kt], bh, acc[nt], 0, 0, 0);
      if (split) {
        s16x8 bl = *(const s16x8*)(BsL + baddr);
        acc[nt] = __builtin_amdgcn_mfma_f32_16x16x32_bf16(al[kt], bh, acc[nt], 0, 0, 0);
        acc[nt] = __builtin_amdgcn_mfma_f32_16x16x32_bf16(ah[kt], bl, acc[nt], 0, 0, 0);
      }
    }
  }

  const int orow0 = rt * 64 + wave * 16 + quad * 4;
  if (mz == 2) {  // X fp32
    #pragma unroll
    for (int nt = 0; nt < 2; ++nt)
      #pragma unroll
      for (int r = 0; r < 4; ++r)
        ws[(orow0 + r) * NH + n0 + nt * 16 + c16] = acc[nt][r];
  } else if (mz < 2) {  // EC1 / EM1: store exp2 of scaled score part, fp32
    float* E = (float*)((char*)ws + (mz == 0 ? 1048576 : 2097152));
    #pragma unroll
    for (int nt = 0; nt < 2; ++nt)
      #pragma unroll
      for (int r = 0; r < 4; ++r)
        E[(orow0 + r) * NH + n0 + nt * 16 + c16] =
            __builtin_amdgcn_exp2f(acc[nt][r]);
  } else {  // C2b / M2b bf16
    unsigned short* O = (unsigned short*)((char*)ws +
        (mz == 3 ? 3670016 : 4194304));
    #pragma unroll
    for (int nt = 0; nt < 2; ++nt)
      #pragma unroll
      for (int r = 0; r < 4; ++r)
        O[(orow0 + r) * NH + n0 + nt * 16 + c16] = f2b(acc[nt][r]);
  }
}

// ---- merged: branch-d MFMA GEMM + tanh reduce, then scores c/b/m,
// softmax(all 4), attend(all 4). One block per (b,p); d-scores stay in LDS.
// Config: __launch_bounds__(256,4) -> 64-VGPR/8-wave regime — measured best
// on the frontier {64r+spill/8w: 100us} < {112r/4w: 139} < {132r/3w: 170}.
__global__ void __launch_bounds__(256, 4) dfused(
    const float* __restrict__ Hp, const float* __restrict__ Hq,
    const float* __restrict__ vd, const float* __restrict__ vc,
    const float* __restrict__ vm, const float* __restrict__ ws,
    float* __restrict__ out)
{
  const int p = blockIdx.x, b = blockIdx.y;
  const int tid = threadIdx.x;
  const int wave = tid >> 6, lane = tid & 63;
  const int quad = lane >> 4, c16 = lane & 15;

  __shared__ __align__(16) char ovl[33792];
  __shared__ __align__(16) float sc4[4 * 256];  // rows: 0=c 1=b 2=d 3=m
  __shared__ __align__(16) float hp_s[256];
  __shared__ __align__(16) float invsum[4];

  short* Bs = (short*)ovl;                       // 32 KB, dphase
  float* vd2_s = (float*)(ovl + 32768);          // 1 KB, dphase
  float* redp = (float*)ovl;                     // 16 KB, fphase
  float* e2c_s = (float*)(ovl + 16384);          // fphase: exp2(c2s)
  float* e2m_s = (float*)(ovl + 17408);          // fphase: exp2(-m2s)
  float* vc2_s = (float*)(ovl + 18432);
  float* vm2_s = (float*)(ovl + 19456);

  const unsigned short* AF = (const unsigned short*)((const char*)ws + 3145728);
  const float* WdT = (const float*)((const char*)ws + 5767168);
  const float* X = ws;
  const float* EC1 = (const float*)((const char*)ws + 1048576);
  const float* EM1 = (const float*)((const char*)ws + 2097152);
  const unsigned short* C2b = (const unsigned short*)((const char*)ws + 3670016);
  const unsigned short* M2b = (const unsigned short*)((const char*)ws + 4194304);

  hp_s[tid] = Hp[(b * NL + p) * ND + tid];
  vd2_s[tid] = 2.0f * vd[tid];
  __syncthreads();

  // ======== phase 1: branch d ====
  {
    const int scol = (tid & 63) * 4;
    const f32x4 hpv = *(const f32x4*)(hp_s + scol);
    const int wq0 = wave * 64;
    const unsigned short* AFw = AF + (b * 4 + wave) * 4 * 8 * 64 * 8;
    const int xswz = (c16 & 7) * 16;

    float sdp[4][4];
    #pragma unroll
    for (int mt = 0; mt < 4; ++mt)
      #pragma unroll
      for (int r = 0; r < 4; ++r) sdp[mt][r] = 0.f;
    float vs2 = 0.f;

    for (int ht = 0; ht < 4; ++ht) {
      const int h0 = ht * 64;
      __syncthreads();
      { // stage Bs[h][k] = bf16(WdT[h0+h][k]*hp[k]); coalesced 1KB/wave
        const float* wsrc = WdT + h0 * 256 + tid * 4;
        #pragma unroll
        for (int i = 0; i < 16; ++i) {
          f32x4 wv = *(const f32x4*)(wsrc + i * 1024);
          const int h = i * 4 + (tid >> 6);
          const unsigned int u0 = cvtpk(wv[0] * hpv[0], wv[1] * hpv[1]);
          const unsigned int u1 = cvtpk(wv[2] * hpv[2], wv[3] * hpv[3]);
          const int baddr = h * 512 + (((tid & 63) * 8) ^ ((h & 7) * 16));
          *(u32x2*)((char*)Bs + baddr) = u32x2{u0, u1};
        }
      }
      __syncthreads();

      f32x4 acc[4][4];
      #pragma unroll
      for (int mt = 0; mt < 4; ++mt)
        #pragma unroll
        for (int nt = 0; nt < 4; ++nt) acc[mt][nt] = f32x4{0.f, 0.f, 0.f, 0.f};

      #pragma unroll 2
      for (int kt = 0; kt < 8; ++kt) {
        s16x8 a8[4];
        #pragma unroll
        for (int mt = 0; mt < 4; ++mt)
          a8[mt] = *(const s16x8*)(AFw + ((mt * 8 + kt) * 64 + lane) * 8);
        #pragma unroll
        for (int nt = 0; nt < 4; ++nt) {
          const int baddr = (nt * 16 + c16) * 512 + ((kt * 64 + quad * 16) ^ xswz);
          s16x8 b8 = *(const s16x8*)((const char*)Bs + baddr);
          #pragma unroll
          for (int mt = 0; mt < 4; ++mt)
            acc[mt][nt] = __builtin_amdgcn_mfma_f32_16x16x32_bf16(
                a8[mt], b8, acc[mt][nt], 0, 0, 0);
        }
      }

      // vd*tanh(z) = vd - vd2*rcp(e^{2z}+1); acc already 2*log2e*z
      #pragma unroll
      for (int nt = 0; nt < 4; ++nt) {
        const float v2 = vd2_s[h0 + nt * 16 + c16];
        vs2 += v2;
        #pragma unroll
        for (int mt = 0; mt < 4; ++mt) {
          #pragma unroll
          for (int r = 0; r < 4; ++r) {
            float e = __builtin_amdgcn_exp2f(acc[mt][nt][r]);
            sdp[mt][r] += v2 * __builtin_amdgcn_rcpf(e + 1.0f);
          }
        }
      }
    }

    // deferred 16-lane reduce -> d-scores into sc4[512+q]
    #pragma unroll
    for (int m = 1; m < 16; m <<= 1) vs2 += __shfl_xor(vs2, m, 64);
    #pragma unroll
    for (int mt = 0; mt < 4; ++mt)
      #pragma unroll
      for (int r = 0; r < 4; ++r) {
        float v = sdp[mt][r];
        #pragma unroll
        for (int m = 1; m < 16; m <<= 1) v += __shfl_xor(v, m, 64);
        if (c16 == 0)
          sc4[512 + wq0 + mt * 16 + quad * 4 + r] = 0.5f * vs2 - v;
      }
  }
  __syncthreads();  // Bs dead; overlay becomes fphase arrays

  { // fphase LDS loads; one exp2 per thread folds c2/m2 into multipliers
    const int r = (b * NL + p) * ND + tid;
    e2c_s[tid] = __builtin_amdgcn_exp2f(b2f(C2b[r]));
    e2m_s[tid] = __builtin_amdgcn_exp2f(-b2f(M2b[r]));
    vc2_s[tid] = 2.0f * vc[tid];
    vm2_s[tid] = 2.0f * vm[tid];
  }
  __syncthreads();

  // ======== phase 2: scores c, b, m (no exp2 in inner loop) =============
  {
    const int qsub = lane >> 4;
    const int hb = c16 * 4;
    float lc = 0.f, lm = 0.f;
    #pragma unroll
    for (int hi = 0; hi < 4; ++hi) {
      const int h = hb + hi * 64;
      #pragma unroll
      for (int i = 0; i < 4; ++i) { lc += vc2_s[h + i]; lm += vm2_s[h + i]; }
    }
    #pragma unroll
    for (int m = 1; m < 16; m <<= 1) {
      lc += __shfl_xor(lc, m, 64);
      lm += __shfl_xor(lm, m, 64);
    }
    const float c0 = 0.5f * lc, m0 = 0.5f * lm;

    for (int qg = 0; qg < 16; ++qg) {
      const int q = wave * 64 + qg * 4 + qsub;
      const float* ecr = EC1 + (b * NL + q) * NH;
      const float* emr = EM1 + (b * NL + q) * NH;
      const float* xr  = X + (b * NL + q) * ND;
      float pcr0 = 0.f, pmr0 = 0.f, pb0 = 0.f;
      float pcr1 = 0.f, pmr1 = 0.f, pb1 = 0.f;
      #pragma unroll
      for (int hi = 0; hi < 4; ++hi) {
        const int h = hb + hi * 64;
        f32x4 ec = *(const f32x4*)(ecr + h);
        f32x4 em = *(const f32x4*)(emr + h);
        f32x4 xv = *(const f32x4*)(xr + h);
        #pragma unroll
        for (int i = 0; i < 4; ++i) {
          float tc = ec[i] * e2c_s[h + i] + 1.0f;
          float tm = em[i] * e2m_s[h + i] + 1.0f;
          if (i & 1) {
            pcr1 += vc2_s[h + i] * __builtin_amdgcn_rcpf(tc);
            pmr1 += vm2_s[h + i] * __builtin_amdgcn_rcpf(tm);
            pb1 += hp_s[h + i] * xv[i];
          } else {
            pcr0 += vc2_s[h + i] * __builtin_amdgcn_rcpf(tc);
            pmr0 += vm2_s[h + i] * __builtin_amdgcn_rcpf(tm);
            pb0 += hp_s[h + i] * xv[i];
          }
        }
      }
      float pcr = pcr0 + pcr1, pmr = pmr0 + pmr1, pb = pb0 + pb1;
      #pragma unroll
      for (int m = 1; m < 16; m <<= 1) {
        pcr += __shfl_xor(pcr, m, 64);
        pmr += __shfl_xor(pmr, m, 64);
        pb  += __shfl_xor(pb, m, 64);
      }
      if (c16 == 0) {
        sc4[q]       = c0 - pcr;
        sc4[256 + q] = pb;
        sc4[768 + q] = m0 - pmr;
      }
    }
  }
  __syncthreads();

  // ======== phase 3: softmax; wave w owns branch w ======================
  {
    float s0 = sc4[wave * 256 + lane];
    float s1 = sc4[wave * 256 + lane + 64];
    float s2 = sc4[wave * 256 + lane + 128];
    float s3 = sc4[wave * 256 + lane + 192];
    float mx = fmaxf(fmaxf(s0, s1), fmaxf(s2, s3));
    #pragma unroll
    for (int m = 1; m < 64; m <<= 1) mx = fmaxf(mx, __shfl_xor(mx, m, 64));
    float e0 = __builtin_amdgcn_exp2f((s0 - mx) * LOG2E);
    float e1 = __builtin_amdgcn_exp2f((s1 - mx) * LOG2E);
    float e2 = __builtin_amdgcn_exp2f((s2 - mx) * LOG2E);
    float e3 = __builtin_amdgcn_exp2f((s3 - mx) * LOG2E);
    float sm = e0 + e1 + e2 + e3;
    #pragma unroll
    for (int m = 1; m < 64; m <<= 1) sm += __shfl_xor(sm, m, 64);
    sc4[wave * 256 + lane]       = e0;
    sc4[wave * 256 + lane + 64]  = e1;
    sc4[wave * 256 + lane + 128] = e2;
    sc4[wave * 256 + lane + 192] = e3;
    if (lane == 0) invsum[wave] = __builtin_amdgcn_rcpf(sm);
  }
  __syncthreads();

  // ======== phase 4: attend =============================================
  {
    const int q0 = wave * 64;
    f32x4 pa0 = {0.f,0.f,0.f,0.f}, pa1 = {0.f,0.f,0.f,0.f};
    f32x4 pa2 = {0.f,0.f,0.f,0.f}, pa3 = {0.f,0.f,0.f,0.f};
    for (int qi = 0; qi < 64; ++qi) {
      const int q = q0 + qi;
      const float ac = sc4[q];
      const float ab = sc4[256 + q];
      const float ad = sc4[512 + q];
      const float am = sc4[768 + q];
      f32x4 hv = *(const f32x4*)(Hq + (b * NL + q) * ND + lane * 4);
      pa0 += ac * hv; pa1 += ab * hv; pa2 += ad * hv; pa3 += am * hv;
    }
    *(f32x4*)(redp + (wave * 4 + 0) * 256 + lane * 4) = pa0;
    *(f32x4*)(redp + (wave * 4 + 1) * 256 + lane * 4) = pa1;
    *(f32x4*)(redp + (wave * 4 + 2) * 256 + lane * 4) = pa2;
    *(f32x4*)(redp + (wave * 4 + 3) * 256 + lane * 4) = pa3;
  }
  __syncthreads();

  // ======== phase 5: cross-wave reduce + normalize + store ==============
  {
    #pragma unroll
    for (int br = 0; br < 4; ++br) {
      float s = redp[(0 * 4 + br) * 256 + tid] + redp[(1 * 4 + br) * 256 + tid]
              + redp[(2 * 4 + br) * 256 + tid] + redp[(3 * 4 + br) * 256 + tid];
      out[((br * NB + b) * NL + p) * ND + tid] = s * invsum[br];
    }
  }
}

extern "C" void kernel_launch(void* const* d_in, const int* in_sizes, int n_in,
                              void* d_out, int out_size, void* d_ws, size_t ws_size,
                              hipStream_t stream) {
  const float* Hp  = (const float*)d_in[0];
  const float* Hq  = (const float*)d_in[1];
  const float* Wc1 = (const float*)d_in[2];
  const float* Wc2 = (const float*)d_in[3];
  const float* vc  = (const float*)d_in[4];
  const float* Wb  = (const float*)d_in[5];
  const float* Wd  = (const float*)d_in[6];
  const float* vd  = (const float*)d_in[7];
  const float* Wm  = (const float*)d_in[8];
  const float* vm  = (const float*)d_in[9];
  float* ws = (float*)d_ws;
  float* out = (float*)d_out;

  hipLaunchKernelGGL(prep, dim3(128, 3), dim3(256), 0, stream,
                     Hq, Wc1, Wc2, Wb, Wm, Wd, ws);
  hipLaunchKernelGGL(gemm5, dim3(16, 8, 5), dim3(256), 0, stream,
                     Hq, Hp, ws);
  hipLaunchKernelGGL(dfused, dim3(256, 4), dim3(256), 0, stream,
                     Hp, Hq, vd, vc, vm, ws, out);
}

// Round 22
// 172.381 us; speedup vs baseline: 1.1935x; 1.0076x over previous
//
#include <hip/hip_runtime.h>

#define LOG2E 1.4426950408889634f
#define TANH_S 2.8853900817779268f  // 2*log2(e)
#define NB 4
#define NL 256
#define ND 256
#define NH 256

typedef __attribute__((ext_vector_type(8))) short s16x8;
typedef __attribute__((ext_vector_type(4))) short s16x4;
typedef __attribute__((ext_vector_type(4))) float f32x4;
typedef __attribute__((ext_vector_type(2))) unsigned int u32x2;
typedef __attribute__((ext_vector_type(4))) unsigned int u32x4;

static __device__ __forceinline__ float b2f(unsigned short u) {
  return __builtin_bit_cast(float, (unsigned int)u << 16);
}
static __device__ __forceinline__ unsigned short f2b(float f) {
  unsigned int x = __builtin_bit_cast(unsigned int, f);
  return (unsigned short)((x + 0x7fffu + ((x >> 16) & 1u)) >> 16);
}
static __device__ __forceinline__ unsigned int cvtpk(float lo, float hi) {
  unsigned int r;
  asm("v_cvt_pk_bf16_f32 %0, %1, %2" : "=v"(r) : "v"(lo), "v"(hi));
  return r;
}

// ws layout (5.75 MB):
//   X    fp32 [0,      1M)    : Hq@Wb
//   EC1  fp32 [1M,     2M)    : exp2(TANH_S*(Hq@Wc1))
//   EM1  fp32 [2M,     3M)    : exp2(TANH_S*(Hq@Wm))
//   AF   bf16 [3M,   3.5M)    : Hq packed in MFMA A-fragment order
//   C2b  bf16 [3.5M,   4M)    : (Hp@Wc2)*TANH_S
//   M2b  bf16 [4M,   4.5M)    : (Hp@Wm)*TANH_S
//   WT   bf16 [4.5M, 5.5M)    : 4x transposed+split weights [n][k]:
//                               w=0 Wc1*S, 1 Wm*S, 2 Wb, 3 Wc2*S (hi+lo 128K each)
//   WdT  fp32 [5.5M, 5.75M)   : (Wd^T)*TANH_S  [h][k] (256 KB)

__global__ void __launch_bounds__(256) prep(
    const float* __restrict__ Hq,
    const float* __restrict__ Wc1, const float* __restrict__ Wc2,
    const float* __restrict__ Wb, const float* __restrict__ Wm,
    const float* __restrict__ Wd, float* __restrict__ ws)
{
  const int which = blockIdx.y;  // 0=AF 1=WdT 2=WT transpose+split
  const int tid = threadIdx.x;
  __shared__ __align__(16) float a_s[8][256];
  if (which == 0) {
    // pack bf16(Hq) into MFMA A-fragment order:
    // AF[((((b*4+w)*4+mt)*8+kt)*64 + quad*16 + c16)*8 + j]
    const int m0 = blockIdx.x * 8;
    unsigned short* AF = (unsigned short*)((char*)ws + 3145728);
    const int row = m0 + (tid >> 5);
    const int grp = tid & 31;
    const int kt = grp >> 2, quad = grp & 3;
    const int k0 = kt * 32 + quad * 8;
    const int bb = row >> 8, q = row & 255;
    const int w = q >> 6, mt = (q >> 4) & 3, c16 = q & 15;
    const float* src = Hq + row * ND + k0;
    f32x4 v0 = *(const f32x4*)(src);
    f32x4 v1 = *(const f32x4*)(src + 4);
    s16x8 o;
    #pragma unroll
    for (int j = 0; j < 4; ++j) { o[j] = (short)f2b(v0[j]); o[4 + j] = (short)f2b(v1[j]); }
    *(s16x8*)(AF + ((((bb * 4 + w) * 4 + mt) * 8 + kt) * 64 + quad * 16 + c16) * 8) = o;
    return;
  }
  if (which == 1) {
    // transpose Wd -> WdT[h][k] fp32 (prescaled by TANH_S) via LDS
    if (blockIdx.x >= 32) return;
    const int k0 = blockIdx.x * 8;
    #pragma unroll
    for (int kk = 0; kk < 8; ++kk)
      a_s[kk][tid] = Wd[(k0 + kk) * NH + tid] * TANH_S;
    __syncthreads();
    float* WdT = (float*)((char*)ws + 5767168);
    f32x4 v0 = {a_s[0][tid], a_s[1][tid], a_s[2][tid], a_s[3][tid]};
    f32x4 v1 = {a_s[4][tid], a_s[5][tid], a_s[6][tid], a_s[7][tid]};
    *(f32x4*)(WdT + tid * 256 + k0) = v0;
    *(f32x4*)(WdT + tid * 256 + k0 + 4) = v1;
    return;
  }
  // which == 2: transpose + bf16-split the 4 score weights
  const int w = blockIdx.x >> 5;          // 0..3
  const int k0 = (blockIdx.x & 31) * 8;
  const float* W = (w == 0) ? Wc1 : (w == 1) ? Wm : (w == 2) ? Wb : Wc2;
  const float scale = (w == 2) ? 1.0f : TANH_S;
  #pragma unroll
  for (int kk = 0; kk < 8; ++kk)
    a_s[kk][tid] = W[(k0 + kk) * NH + tid] * scale;
  __syncthreads();
  unsigned short* WT = (unsigned short*)((char*)ws + 4718592) + w * 131072;
  s16x8 hi, lo;
  #pragma unroll
  for (int kk = 0; kk < 8; ++kk) {
    float v = a_s[kk][tid];
    unsigned short h = f2b(v);
    hi[kk] = (short)h;
    lo[kk] = (short)f2b(v - b2f(h));
  }
  *(s16x8*)(WT + tid * 256 + k0) = hi;
  *(s16x8*)(WT + 65536 + tid * 256 + k0) = lo;
}

// ---- all 5 prep GEMMs via MFMA, LDS-staged weights.
// grid (16 rowtiles, 8 coltiles, 5 matrices) = 640 blocks; tile 64 rows x 32 cols.
// z: 0=EC1(Hq,w0,exp2) 1=EM1(Hq,w1,exp2) 2=X(Hq,w2) 3=C2b(Hp,w3) 4=M2b(Hp,w1)
// 3-MFMA compensated split ONLY for X (mz==2, raw softmax scores).
__global__ void __launch_bounds__(256) gemm5(
    const float* __restrict__ Hq, const float* __restrict__ Hp,
    float* __restrict__ ws)
{
  const int rt = blockIdx.x, ct = blockIdx.y, mz = blockIdx.z;
  const int tid = threadIdx.x;
  const int wave = tid >> 6, lane = tid & 63;
  const int quad = lane >> 4, c16 = lane & 15;

  __shared__ __align__(16) char bs[32768];  // BsH 16K | BsL 16K
  char* BsH = bs;
  char* BsL = bs + 16384;

  const int w = (mz == 4) ? 1 : ((mz == 3) ? 3 : mz);
  const float* A = (mz >= 3) ? Hp : Hq;
  const int n0 = ct * 32;
  const bool split = (mz == 2);

  { // stage WH (and WL if split) rows [n0,n0+32) x k[0,256), XOR swizzle
    const unsigned short* WTw = (const unsigned short*)((const char*)ws + 4718592)
                                + w * 131072 + n0 * 256;
    const int soff = (tid & 31) * 16;
    #pragma unroll
    for (int i = 0; i < 4; ++i) {
      const int h = i * 8 + (tid >> 5);
      const int doff = h * 512 + (soff ^ ((h & 7) * 16));
      u32x4 vh = *(const u32x4*)((const char*)WTw + h * 512 + soff);
      *(u32x4*)(BsH + doff) = vh;
      if (split) {
        u32x4 vl = *(const u32x4*)((const char*)WTw + 131072 + h * 512 + soff);
        *(u32x4*)(BsL + doff) = vl;
      }
    }
  }

  // A fragments: row = rt*64 + wave*16 + c16; hi always, lo only if split
  const int row = rt * 64 + wave * 16 + c16;
  s16x8 ah[8], al[8];
  #pragma unroll
  for (int kt = 0; kt < 8; ++kt) {
    const float* src = A + row * ND + kt * 32 + quad * 8;
    f32x4 v0 = *(const f32x4*)(src);
    f32x4 v1 = *(const f32x4*)(src + 4);
    #pragma unroll
    for (int j = 0; j < 4; ++j) {
      unsigned short h0 = f2b(v0[j]);
      ah[kt][j] = (short)h0;
      unsigned short h1 = f2b(v1[j]);
      ah[kt][4 + j] = (short)h1;
      if (split) {
        al[kt][j] = (short)f2b(v0[j] - b2f(h0));
        al[kt][4 + j] = (short)f2b(v1[j] - b2f(h1));
      }
    }
  }
  __syncthreads();

  f32x4 acc[2];
  #pragma unroll
  for (int nt = 0; nt < 2; ++nt) acc[nt] = f32x4{0.f, 0.f, 0.f, 0.f};

  const int xswz = (c16 & 7) * 16;
  #pragma unroll
  for (int kt = 0; kt < 8; ++kt) {
    #pragma unroll
    for (int nt = 0; nt < 2; ++nt) {
      const int baddr = (nt * 16 + c16) * 512 + ((kt * 64 + quad * 16) ^ xswz);
      s16x8 bh = *(const s16x8*)(BsH + baddr);
      acc[nt] = __builtin_amdgcn_mfma_f32_16x16x32_bf16(ah[kt], bh, acc[nt], 0, 0, 0);
      if (split) {
        s16x8 bl = *(const s16x8*)(BsL + baddr);
        acc[nt] = __builtin_amdgcn_mfma_f32_16x16x32_bf16(al[kt], bh, acc[nt], 0, 0, 0);
        acc[nt] = __builtin_amdgcn_mfma_f32_16x16x32_bf16(ah[kt], bl, acc[nt], 0, 0, 0);
      }
    }
  }

  const int orow0 = rt * 64 + wave * 16 + quad * 4;
  if (mz == 2) {  // X fp32
    #pragma unroll
    for (int nt = 0; nt < 2; ++nt)
      #pragma unroll
      for (int r = 0; r < 4; ++r)
        ws[(orow0 + r) * NH + n0 + nt * 16 + c16] = acc[nt][r];
  } else if (mz < 2) {  // EC1 / EM1: store exp2 of scaled score part, fp32
    float* E = (float*)((char*)ws + (mz == 0 ? 1048576 : 2097152));
    #pragma unroll
    for (int nt = 0; nt < 2; ++nt)
      #pragma unroll
      for (int r = 0; r < 4; ++r)
        E[(orow0 + r) * NH + n0 + nt * 16 + c16] =
            __builtin_amdgcn_exp2f(acc[nt][r]);
  } else {  // C2b / M2b bf16
    unsigned short* O = (unsigned short*)((char*)ws +
        (mz == 3 ? 3670016 : 4194304));
    #pragma unroll
    for (int nt = 0; nt < 2; ++nt)
      #pragma unroll
      for (int r = 0; r < 4; ++r)
        O[(orow0 + r) * NH + n0 + nt * 16 + c16] = f2b(acc[nt][r]);
  }
}

// ---- merged: branch-d MFMA GEMM + tanh reduce, then scores c/b/m,
// softmax(all 4), attend(all 4). One block per (b,p); d-scores stay in LDS.
// Config: __launch_bounds__(256,4) -> 64-VGPR/8-wave regime (measured best).
// v20: phase-1 mh RUNTIME loop (not unrolled): two acc[2][4] passes per ht
// shrink peak live ~115 -> ~70 regs, cutting the ~50-reg spill churn
// (23.5 MB WRITE) to ~5 regs, with a SMALLER compiled body than v18.
__global__ void __launch_bounds__(256, 4) dfused(
    const float* __restrict__ Hp, const float* __restrict__ Hq,
    const float* __restrict__ vd, const float* __restrict__ vc,
    const float* __restrict__ vm, const float* __restrict__ ws,
    float* __restrict__ out)
{
  const int p = blockIdx.x, b = blockIdx.y;
  const int tid = threadIdx.x;
  const int wave = tid >> 6, lane = tid & 63;
  const int quad = lane >> 4, c16 = lane & 15;

  __shared__ __align__(16) char ovl[33792];
  __shared__ __align__(16) float sc4[4 * 256];  // rows: 0=c 1=b 2=d 3=m
  __shared__ __align__(16) float hp_s[256];
  __shared__ __align__(16) float invsum[4];

  short* Bs = (short*)ovl;                       // 32 KB, dphase
  float* vd2_s = (float*)(ovl + 32768);          // 1 KB, dphase
  float* redp = (float*)ovl;                     // 16 KB, fphase
  float* e2c_s = (float*)(ovl + 16384);          // fphase: exp2(c2s)
  float* e2m_s = (float*)(ovl + 17408);          // fphase: exp2(-m2s)
  float* vc2_s = (float*)(ovl + 18432);
  float* vm2_s = (float*)(ovl + 19456);

  const unsigned short* AF = (const unsigned short*)((const char*)ws + 3145728);
  const float* WdT = (const float*)((const char*)ws + 5767168);
  const float* X = ws;
  const float* EC1 = (const float*)((const char*)ws + 1048576);
  const float* EM1 = (const float*)((const char*)ws + 2097152);
  const unsigned short* C2b = (const unsigned short*)((const char*)ws + 3670016);
  const unsigned short* M2b = (const unsigned short*)((const char*)ws + 4194304);

  hp_s[tid] = Hp[(b * NL + p) * ND + tid];
  vd2_s[tid] = 2.0f * vd[tid];
  __syncthreads();

  // ======== phase 1: branch d (runtime mh loop: two acc[2][4] passes) ====
  {
    const int scol = (tid & 63) * 4;
    const f32x4 hpv = *(const f32x4*)(hp_s + scol);
    const int wq0 = wave * 64;
    const unsigned short* AFw = AF + (b * 4 + wave) * 4 * 8 * 64 * 8;
    const int xswz = (c16 & 7) * 16;

    float sdp[4][4];
    #pragma unroll
    for (int mt = 0; mt < 4; ++mt)
      #pragma unroll
      for (int r = 0; r < 4; ++r) sdp[mt][r] = 0.f;
    float vs2 = 0.f;

    for (int ht = 0; ht < 4; ++ht) {
      const int h0 = ht * 64;
      __syncthreads();
      { // stage Bs[h][k] = bf16(WdT[h0+h][k]*hp[k]); coalesced 1KB/wave
        const float* wsrc = WdT + h0 * 256 + tid * 4;
        #pragma unroll
        for (int i = 0; i < 16; ++i) {
          f32x4 wv = *(const f32x4*)(wsrc + i * 1024);
          const int h = i * 4 + (tid >> 6);
          const unsigned int u0 = cvtpk(wv[0] * hpv[0], wv[1] * hpv[1]);
          const unsigned int u1 = cvtpk(wv[2] * hpv[2], wv[3] * hpv[3]);
          const int baddr = h * 512 + (((tid & 63) * 8) ^ ((h & 7) * 16));
          *(u32x2*)((char*)Bs + baddr) = u32x2{u0, u1};
        }
      }
      __syncthreads();

      // vs2 accumulation once per ht
      #pragma unroll
      for (int nt = 0; nt < 4; ++nt) vs2 += vd2_s[h0 + nt * 16 + c16];

      for (int mh = 0; mh < 2; ++mh) {  // runtime loop — small code body
        f32x4 acc[2][4];
        #pragma unroll
        for (int mi = 0; mi < 2; ++mi)
          #pragma unroll
          for (int nt = 0; nt < 4; ++nt) acc[mi][nt] = f32x4{0.f, 0.f, 0.f, 0.f};

        const unsigned short* AFm = AFw + (mh * 2) * 8 * 64 * 8;
        #pragma unroll 2
        for (int kt = 0; kt < 8; ++kt) {
          s16x8 a0 = *(const s16x8*)(AFm + (kt * 64 + lane) * 8);
          s16x8 a1 = *(const s16x8*)(AFm + ((8 + kt) * 64 + lane) * 8);
          #pragma unroll
          for (int nt = 0; nt < 4; ++nt) {
            const int baddr = (nt * 16 + c16) * 512 + ((kt * 64 + quad * 16) ^ xswz);
            s16x8 b8 = *(const s16x8*)((const char*)Bs + baddr);
            acc[0][nt] = __builtin_amdgcn_mfma_f32_16x16x32_bf16(
                a0, b8, acc[0][nt], 0, 0, 0);
            acc[1][nt] = __builtin_amdgcn_mfma_f32_16x16x32_bf16(
                a1, b8, acc[1][nt], 0, 0, 0);
          }
        }

        // vd*tanh(z) = vd - vd2*rcp(e^{2z}+1); acc already 2*log2e*z
        #pragma unroll
        for (int nt = 0; nt < 4; ++nt) {
          const float v2 = vd2_s[h0 + nt * 16 + c16];
          #pragma unroll
          for (int mi = 0; mi < 2; ++mi) {
            #pragma unroll
            for (int r = 0; r < 4; ++r) {
              float e = __builtin_amdgcn_exp2f(acc[mi][nt][r]);
              sdp[mh * 2 + mi][r] += v2 * __builtin_amdgcn_rcpf(e + 1.0f);
            }
          }
        }
      }
    }

    // deferred 16-lane reduce -> d-scores into sc4[512+q]
    #pragma unroll
    for (int m = 1; m < 16; m <<= 1) vs2 += __shfl_xor(vs2, m, 64);
    #pragma unroll
    for (int mt = 0; mt < 4; ++mt)
      #pragma unroll
      for (int r = 0; r < 4; ++r) {
        float v = sdp[mt][r];
        #pragma unroll
        for (int m = 1; m < 16; m <<= 1) v += __shfl_xor(v, m, 64);
        if (c16 == 0)
          sc4[512 + wq0 + mt * 16 + quad * 4 + r] = 0.5f * vs2 - v;
      }
  }
  __syncthreads();  // Bs dead; overlay becomes fphase arrays

  { // fphase LDS loads; one exp2 per thread folds c2/m2 into multipliers
    const int r = (b * NL + p) * ND + tid;
    e2c_s[tid] = __builtin_amdgcn_exp2f(b2f(C2b[r]));
    e2m_s[tid] = __builtin_amdgcn_exp2f(-b2f(M2b[r]));
    vc2_s[tid] = 2.0f * vc[tid];
    vm2_s[tid] = 2.0f * vm[tid];
  }
  __syncthreads();

  // ======== phase 2: scores c, b, m (no exp2 in inner loop) =============
  {
    const int qsub = lane >> 4;
    const int hb = c16 * 4;
    float lc = 0.f, lm = 0.f;
    #pragma unroll
    for (int hi = 0; hi < 4; ++hi) {
      const int h = hb + hi * 64;
      #pragma unroll
      for (int i = 0; i < 4; ++i) { lc += vc2_s[h + i]; lm += vm2_s[h + i]; }
    }
    #pragma unroll
    for (int m = 1; m < 16; m <<= 1) {
      lc += __shfl_xor(lc, m, 64);
      lm += __shfl_xor(lm, m, 64);
    }
    const float c0 = 0.5f * lc, m0 = 0.5f * lm;

    for (int qg = 0; qg < 16; ++qg) {
      const int q = wave * 64 + qg * 4 + qsub;
      const float* ecr = EC1 + (b * NL + q) * NH;
      const float* emr = EM1 + (b * NL + q) * NH;
      const float* xr  = X + (b * NL + q) * ND;
      float pcr0 = 0.f, pmr0 = 0.f, pb0 = 0.f;
      float pcr1 = 0.f, pmr1 = 0.f, pb1 = 0.f;
      #pragma unroll
      for (int hi = 0; hi < 4; ++hi) {
        const int h = hb + hi * 64;
        f32x4 ec = *(const f32x4*)(ecr + h);
        f32x4 em = *(const f32x4*)(emr + h);
        f32x4 xv = *(const f32x4*)(xr + h);
        #pragma unroll
        for (int i = 0; i < 4; ++i) {
          float tc = ec[i] * e2c_s[h + i] + 1.0f;
          float tm = em[i] * e2m_s[h + i] + 1.0f;
          if (i & 1) {
            pcr1 += vc2_s[h + i] * __builtin_amdgcn_rcpf(tc);
            pmr1 += vm2_s[h + i] * __builtin_amdgcn_rcpf(tm);
            pb1 += hp_s[h + i] * xv[i];
          } else {
            pcr0 += vc2_s[h + i] * __builtin_amdgcn_rcpf(tc);
            pmr0 += vm2_s[h + i] * __builtin_amdgcn_rcpf(tm);
            pb0 += hp_s[h + i] * xv[i];
          }
        }
      }
      float pcr = pcr0 + pcr1, pmr = pmr0 + pmr1, pb = pb0 + pb1;
      #pragma unroll
      for (int m = 1; m < 16; m <<= 1) {
        pcr += __shfl_xor(pcr, m, 64);
        pmr += __shfl_xor(pmr, m, 64);
        pb  += __shfl_xor(pb, m, 64);
      }
      if (c16 == 0) {
        sc4[q]       = c0 - pcr;
        sc4[256 + q] = pb;
        sc4[768 + q] = m0 - pmr;
      }
    }
  }
  __syncthreads();

  // ======== phase 3: softmax; wave w owns branch w ======================
  {
    float s0 = sc4[wave * 256 + lane];
    float s1 = sc4[wave * 256 + lane + 64];
    float s2 = sc4[wave * 256 + lane + 128];
    float s3 = sc4[wave * 256 + lane + 192];
    float mx = fmaxf(fmaxf(s0, s1), fmaxf(s2, s3));
    #pragma unroll
    for (int m = 1; m < 64; m <<= 1) mx = fmaxf(mx, __shfl_xor(mx, m, 64));
    float e0 = __builtin_amdgcn_exp2f((s0 - mx) * LOG2E);
    float e1 = __builtin_amdgcn_exp2f((s1 - mx) * LOG2E);
    float e2 = __builtin_amdgcn_exp2f((s2 - mx) * LOG2E);
    float e3 = __builtin_amdgcn_exp2f((s3 - mx) * LOG2E);
    float sm = e0 + e1 + e2 + e3;
    #pragma unroll
    for (int m = 1; m < 64; m <<= 1) sm += __shfl_xor(sm, m, 64);
    sc4[wave * 256 + lane]       = e0;
    sc4[wave * 256 + lane + 64]  = e1;
    sc4[wave * 256 + lane + 128] = e2;
    sc4[wave * 256 + lane + 192] = e3;
    if (lane == 0) invsum[wave] = __builtin_amdgcn_rcpf(sm);
  }
  __syncthreads();

  // ======== phase 4: attend =============================================
  {
    const int q0 = wave * 64;
    f32x4 pa0 = {0.f,0.f,0.f,0.f}, pa1 = {0.f,0.f,0.f,0.f};
    f32x4 pa2 = {0.f,0.f,0.f,0.f}, pa3 = {0.f,0.f,0.f,0.f};
    for (int qi = 0; qi < 64; ++qi) {
      const int q = q0 + qi;
      const float ac = sc4[q];
      const float ab = sc4[256 + q];
      const float ad = sc4[512 + q];
      const float am = sc4[768 + q];
      f32x4 hv = *(const f32x4*)(Hq + (b * NL + q) * ND + lane * 4);
      pa0 += ac * hv; pa1 += ab * hv; pa2 += ad * hv; pa3 += am * hv;
    }
    *(f32x4*)(redp + (wave * 4 + 0) * 256 + lane * 4) = pa0;
    *(f32x4*)(redp + (wave * 4 + 1) * 256 + lane * 4) = pa1;
    *(f32x4*)(redp + (wave * 4 + 2) * 256 + lane * 4) = pa2;
    *(f32x4*)(redp + (wave * 4 + 3) * 256 + lane * 4) = pa3;
  }
  __syncthreads();

  // ======== phase 5: cross-wave reduce + normalize + store ==============
  {
    #pragma unroll
    for (int br = 0; br < 4; ++br) {
      float s = redp[(0 * 4 + br) * 256 + tid] + redp[(1 * 4 + br) * 256 + tid]
              + redp[(2 * 4 + br) * 256 + tid] + redp[(3 * 4 + br) * 256 + tid];
      out[((br * NB + b) * NL + p) * ND + tid] = s * invsum[br];
    }
  }
}

extern "C" void kernel_launch(void* const* d_in, const int* in_sizes, int n_in,
                              void* d_out, int out_size, void* d_ws, size_t ws_size,
                              hipStream_t stream) {
  const float* Hp  = (const float*)d_in[0];
  const float* Hq  = (const float*)d_in[1];
  const float* Wc1 = (const float*)d_in[2];
  const float* Wc2 = (const float*)d_in[3];
  const float* vc  = (const float*)d_in[4];
  const float* Wb  = (const float*)d_in[5];
  const float* Wd  = (const float*)d_in[6];
  const float* vd  = (const float*)d_in[7];
  const float* Wm  = (const float*)d_in[8];
  const float* vm  = (const float*)d_in[9];
  float* ws = (float*)d_ws;
  float* out = (float*)d_out;

  hipLaunchKernelGGL(prep, dim3(128, 3), dim3(256), 0, stream,
                     Hq, Wc1, Wc2, Wb, Wm, Wd, ws);
  hipLaunchKernelGGL(gemm5, dim3(16, 8, 5), dim3(256), 0, stream,
                     Hq, Hp, ws);
  hipLaunchKernelGGL(dfused, dim3(256, 4), dim3(256), 0, stream,
                     Hp, Hq, vd, vc, vm, ws, out);
}

// Round 23
// 170.317 us; speedup vs baseline: 1.2079x; 1.0121x over previous
//
#include <hip/hip_runtime.h>

#define LOG2E 1.4426950408889634f
#define TANH_S 2.8853900817779268f  // 2*log2(e)
#define NB 4
#define NL 256
#define ND 256
#define NH 256

typedef __attribute__((ext_vector_type(8))) short s16x8;
typedef __attribute__((ext_vector_type(4))) short s16x4;
typedef __attribute__((ext_vector_type(4))) float f32x4;
typedef __attribute__((ext_vector_type(2))) unsigned int u32x2;
typedef __attribute__((ext_vector_type(4))) unsigned int u32x4;

static __device__ __forceinline__ float b2f(unsigned short u) {
  return __builtin_bit_cast(float, (unsigned int)u << 16);
}
static __device__ __forceinline__ unsigned short f2b(float f) {
  unsigned int x = __builtin_bit_cast(unsigned int, f);
  return (unsigned short)((x + 0x7fffu + ((x >> 16) & 1u)) >> 16);
}
static __device__ __forceinline__ unsigned int cvtpk(float lo, float hi) {
  unsigned int r;
  asm("v_cvt_pk_bf16_f32 %0, %1, %2" : "=v"(r) : "v"(lo), "v"(hi));
  return r;
}

// ws layout (5.75 MB):
//   X    fp32 [0,      1M)    : Hq@Wb
//   EC1  fp32 [1M,     2M)    : exp2(TANH_S*(Hq@Wc1))
//   EM1  fp32 [2M,     3M)    : exp2(TANH_S*(Hq@Wm))
//   AF   bf16 [3M,   3.5M)    : Hq packed in MFMA A-fragment order
//   C2b  bf16 [3.5M,   4M)    : (Hp@Wc2)*TANH_S
//   M2b  bf16 [4M,   4.5M)    : (Hp@Wm)*TANH_S
//   WT   bf16 [4.5M, 5.5M)    : 4x transposed+split weights [n][k]:
//                               w=0 Wc1*S, 1 Wm*S, 2 Wb, 3 Wc2*S (hi+lo 128K each)
//   WdT  fp32 [5.5M, 5.75M)   : (Wd^T)*TANH_S  [h][k] (256 KB)

__global__ void __launch_bounds__(256) prep(
    const float* __restrict__ Hq,
    const float* __restrict__ Wc1, const float* __restrict__ Wc2,
    const float* __restrict__ Wb, const float* __restrict__ Wm,
    const float* __restrict__ Wd, float* __restrict__ ws)
{
  const int which = blockIdx.y;  // 0=AF 1=WdT 2=WT transpose+split
  const int tid = threadIdx.x;
  __shared__ __align__(16) float a_s[8][256];
  if (which == 0) {
    // pack bf16(Hq) into MFMA A-fragment order:
    // AF[((((b*4+w)*4+mt)*8+kt)*64 + quad*16 + c16)*8 + j]
    const int m0 = blockIdx.x * 8;
    unsigned short* AF = (unsigned short*)((char*)ws + 3145728);
    const int row = m0 + (tid >> 5);
    const int grp = tid & 31;
    const int kt = grp >> 2, quad = grp & 3;
    const int k0 = kt * 32 + quad * 8;
    const int bb = row >> 8, q = row & 255;
    const int w = q >> 6, mt = (q >> 4) & 3, c16 = q & 15;
    const float* src = Hq + row * ND + k0;
    f32x4 v0 = *(const f32x4*)(src);
    f32x4 v1 = *(const f32x4*)(src + 4);
    s16x8 o;
    #pragma unroll
    for (int j = 0; j < 4; ++j) { o[j] = (short)f2b(v0[j]); o[4 + j] = (short)f2b(v1[j]); }
    *(s16x8*)(AF + ((((bb * 4 + w) * 4 + mt) * 8 + kt) * 64 + quad * 16 + c16) * 8) = o;
    return;
  }
  if (which == 1) {
    // transpose Wd -> WdT[h][k] fp32 (prescaled by TANH_S) via LDS
    if (blockIdx.x >= 32) return;
    const int k0 = blockIdx.x * 8;
    #pragma unroll
    for (int kk = 0; kk < 8; ++kk)
      a_s[kk][tid] = Wd[(k0 + kk) * NH + tid] * TANH_S;
    __syncthreads();
    float* WdT = (float*)((char*)ws + 5767168);
    f32x4 v0 = {a_s[0][tid], a_s[1][tid], a_s[2][tid], a_s[3][tid]};
    f32x4 v1 = {a_s[4][tid], a_s[5][tid], a_s[6][tid], a_s[7][tid]};
    *(f32x4*)(WdT + tid * 256 + k0) = v0;
    *(f32x4*)(WdT + tid * 256 + k0 + 4) = v1;
    return;
  }
  // which == 2: transpose + bf16-split the 4 score weights
  const int w = blockIdx.x >> 5;          // 0..3
  const int k0 = (blockIdx.x & 31) * 8;
  const float* W = (w == 0) ? Wc1 : (w == 1) ? Wm : (w == 2) ? Wb : Wc2;
  const float scale = (w == 2) ? 1.0f : TANH_S;
  #pragma unroll
  for (int kk = 0; kk < 8; ++kk)
    a_s[kk][tid] = W[(k0 + kk) * NH + tid] * scale;
  __syncthreads();
  unsigned short* WT = (unsigned short*)((char*)ws + 4718592) + w * 131072;
  s16x8 hi, lo;
  #pragma unroll
  for (int kk = 0; kk < 8; ++kk) {
    float v = a_s[kk][tid];
    unsigned short h = f2b(v);
    hi[kk] = (short)h;
    lo[kk] = (short)f2b(v - b2f(h));
  }
  *(s16x8*)(WT + tid * 256 + k0) = hi;
  *(s16x8*)(WT + 65536 + tid * 256 + k0) = lo;
}

// ---- all 5 prep GEMMs via MFMA, LDS-staged weights.
// grid (16 rowtiles, 8 coltiles, 5 matrices) = 640 blocks; tile 64 rows x 32 cols.
// z: 0=EC1(Hq,w0,exp2) 1=EM1(Hq,w1,exp2) 2=X(Hq,w2) 3=C2b(Hp,w3) 4=M2b(Hp,w1)
// 3-MFMA compensated split ONLY for X (mz==2, raw softmax scores).
__global__ void __launch_bounds__(256) gemm5(
    const float* __restrict__ Hq, const float* __restrict__ Hp,
    float* __restrict__ ws)
{
  const int rt = blockIdx.x, ct = blockIdx.y, mz = blockIdx.z;
  const int tid = threadIdx.x;
  const int wave = tid >> 6, lane = tid & 63;
  const int quad = lane >> 4, c16 = lane & 15;

  __shared__ __align__(16) char bs[32768];  // BsH 16K | BsL 16K
  char* BsH = bs;
  char* BsL = bs + 16384;

  const int w = (mz == 4) ? 1 : ((mz == 3) ? 3 : mz);
  const float* A = (mz >= 3) ? Hp : Hq;
  const int n0 = ct * 32;
  const bool split = (mz == 2);

  { // stage WH (and WL if split) rows [n0,n0+32) x k[0,256), XOR swizzle
    const unsigned short* WTw = (const unsigned short*)((const char*)ws + 4718592)
                                + w * 131072 + n0 * 256;
    const int soff = (tid & 31) * 16;
    #pragma unroll
    for (int i = 0; i < 4; ++i) {
      const int h = i * 8 + (tid >> 5);
      const int doff = h * 512 + (soff ^ ((h & 7) * 16));
      u32x4 vh = *(const u32x4*)((const char*)WTw + h * 512 + soff);
      *(u32x4*)(BsH + doff) = vh;
      if (split) {
        u32x4 vl = *(const u32x4*)((const char*)WTw + 131072 + h * 512 + soff);
        *(u32x4*)(BsL + doff) = vl;
      }
    }
  }

  // A fragments: row = rt*64 + wave*16 + c16; hi always, lo only if split
  const int row = rt * 64 + wave * 16 + c16;
  s16x8 ah[8], al[8];
  #pragma unroll
  for (int kt = 0; kt < 8; ++kt) {
    const float* src = A + row * ND + kt * 32 + quad * 8;
    f32x4 v0 = *(const f32x4*)(src);
    f32x4 v1 = *(const f32x4*)(src + 4);
    #pragma unroll
    for (int j = 0; j < 4; ++j) {
      unsigned short h0 = f2b(v0[j]);
      ah[kt][j] = (short)h0;
      unsigned short h1 = f2b(v1[j]);
      ah[kt][4 + j] = (short)h1;
      if (split) {
        al[kt][j] = (short)f2b(v0[j] - b2f(h0));
        al[kt][4 + j] = (short)f2b(v1[j] - b2f(h1));
      }
    }
  }
  __syncthreads();

  f32x4 acc[2];
  #pragma unroll
  for (int nt = 0; nt < 2; ++nt) acc[nt] = f32x4{0.f, 0.f, 0.f, 0.f};

  const int xswz = (c16 & 7) * 16;
  #pragma unroll
  for (int kt = 0; kt < 8; ++kt) {
    #pragma unroll
    for (int nt = 0; nt < 2; ++nt) {
      const int baddr = (nt * 16 + c16) * 512 + ((kt * 64 + quad * 16) ^ xswz);
      s16x8 bh = *(const s16x8*)(BsH + baddr);
      acc[nt] = __builtin_amdgcn_mfma_f32_16x16x32_bf16(ah[kt], bh, acc[nt], 0, 0, 0);
      if (split) {
        s16x8 bl = *(const s16x8*)(BsL + baddr);
        acc[nt] = __builtin_amdgcn_mfma_f32_16x16x32_bf16(al[kt], bh, acc[nt], 0, 0, 0);
        acc[nt] = __builtin_amdgcn_mfma_f32_16x16x32_bf16(ah[kt], bl, acc[nt], 0, 0, 0);
      }
    }
  }

  const int orow0 = rt * 64 + wave * 16 + quad * 4;
  if (mz == 2) {  // X fp32
    #pragma unroll
    for (int nt = 0; nt < 2; ++nt)
      #pragma unroll
      for (int r = 0; r < 4; ++r)
        ws[(orow0 + r) * NH + n0 + nt * 16 + c16] = acc[nt][r];
  } else if (mz < 2) {  // EC1 / EM1: store exp2 of scaled score part, fp32
    float* E = (float*)((char*)ws + (mz == 0 ? 1048576 : 2097152));
    #pragma unroll
    for (int nt = 0; nt < 2; ++nt)
      #pragma unroll
      for (int r = 0; r < 4; ++r)
        E[(orow0 + r) * NH + n0 + nt * 16 + c16] =
            __builtin_amdgcn_exp2f(acc[nt][r]);
  } else {  // C2b / M2b bf16
    unsigned short* O = (unsigned short*)((char*)ws +
        (mz == 3 ? 3670016 : 4194304));
    #pragma unroll
    for (int nt = 0; nt < 2; ++nt)
      #pragma unroll
      for (int r = 0; r < 4; ++r)
        O[(orow0 + r) * NH + n0 + nt * 16 + c16] = f2b(acc[nt][r]);
  }
}

// ---- merged: branch-d MFMA GEMM + tanh reduce, then scores c/b/m,
// softmax(all 4), attend(all 4). One block per (b,p); d-scores stay in LDS.
// Config: __launch_bounds__(256,4) -> 64-VGPR/8-wave regime (measured best)
// + runtime-mh split (R22) + v21: XCD-chunked block swizzle. Per-b working
// set (X/EC1/EM1/AF/Hq slices) ~2MB fits one XCD's 4MB L2; default
// round-robin interleaves all 4 b's (~8MB/XCD -> thrash, 28MB HBM FETCH).
// Bijective since 1024 %% 8 == 0.
__global__ void __launch_bounds__(256, 4) dfused(
    const float* __restrict__ Hp, const float* __restrict__ Hq,
    const float* __restrict__ vd, const float* __restrict__ vc,
    const float* __restrict__ vm, const float* __restrict__ ws,
    float* __restrict__ out)
{
  const int orig = blockIdx.y * 256 + blockIdx.x;
  const int swz = (orig & 7) * 128 + (orig >> 3);  // XCD-chunked, bijective
  const int p = swz & 255, b = swz >> 8;
  const int tid = threadIdx.x;
  const int wave = tid >> 6, lane = tid & 63;
  const int quad = lane >> 4, c16 = lane & 15;

  __shared__ __align__(16) char ovl[33792];
  __shared__ __align__(16) float sc4[4 * 256];  // rows: 0=c 1=b 2=d 3=m
  __shared__ __align__(16) float hp_s[256];
  __shared__ __align__(16) float invsum[4];

  short* Bs = (short*)ovl;                       // 32 KB, dphase
  float* vd2_s = (float*)(ovl + 32768);          // 1 KB, dphase
  float* redp = (float*)ovl;                     // 16 KB, fphase
  float* e2c_s = (float*)(ovl + 16384);          // fphase: exp2(c2s)
  float* e2m_s = (float*)(ovl + 17408);          // fphase: exp2(-m2s)
  float* vc2_s = (float*)(ovl + 18432);
  float* vm2_s = (float*)(ovl + 19456);

  const unsigned short* AF = (const unsigned short*)((const char*)ws + 3145728);
  const float* WdT = (const float*)((const char*)ws + 5767168);
  const float* X = ws;
  const float* EC1 = (const float*)((const char*)ws + 1048576);
  const float* EM1 = (const float*)((const char*)ws + 2097152);
  const unsigned short* C2b = (const unsigned short*)((const char*)ws + 3670016);
  const unsigned short* M2b = (const unsigned short*)((const char*)ws + 4194304);

  hp_s[tid] = Hp[(b * NL + p) * ND + tid];
  vd2_s[tid] = 2.0f * vd[tid];
  __syncthreads();

  // ======== phase 1: branch d (runtime mh loop: two acc[2][4] passes) ====
  {
    const int scol = (tid & 63) * 4;
    const f32x4 hpv = *(const f32x4*)(hp_s + scol);
    const int wq0 = wave * 64;
    const unsigned short* AFw = AF + (b * 4 + wave) * 4 * 8 * 64 * 8;
    const int xswz = (c16 & 7) * 16;

    float sdp[4][4];
    #pragma unroll
    for (int mt = 0; mt < 4; ++mt)
      #pragma unroll
      for (int r = 0; r < 4; ++r) sdp[mt][r] = 0.f;
    float vs2 = 0.f;

    for (int ht = 0; ht < 4; ++ht) {
      const int h0 = ht * 64;
      __syncthreads();
      { // stage Bs[h][k] = bf16(WdT[h0+h][k]*hp[k]); coalesced 1KB/wave
        const float* wsrc = WdT + h0 * 256 + tid * 4;
        #pragma unroll
        for (int i = 0; i < 16; ++i) {
          f32x4 wv = *(const f32x4*)(wsrc + i * 1024);
          const int h = i * 4 + (tid >> 6);
          const unsigned int u0 = cvtpk(wv[0] * hpv[0], wv[1] * hpv[1]);
          const unsigned int u1 = cvtpk(wv[2] * hpv[2], wv[3] * hpv[3]);
          const int baddr = h * 512 + (((tid & 63) * 8) ^ ((h & 7) * 16));
          *(u32x2*)((char*)Bs + baddr) = u32x2{u0, u1};
        }
      }
      __syncthreads();

      // vs2 accumulation once per ht
      #pragma unroll
      for (int nt = 0; nt < 4; ++nt) vs2 += vd2_s[h0 + nt * 16 + c16];

      for (int mh = 0; mh < 2; ++mh) {  // runtime loop — small code body
        f32x4 acc[2][4];
        #pragma unroll
        for (int mi = 0; mi < 2; ++mi)
          #pragma unroll
          for (int nt = 0; nt < 4; ++nt) acc[mi][nt] = f32x4{0.f, 0.f, 0.f, 0.f};

        const unsigned short* AFm = AFw + (mh * 2) * 8 * 64 * 8;
        #pragma unroll 2
        for (int kt = 0; kt < 8; ++kt) {
          s16x8 a0 = *(const s16x8*)(AFm + (kt * 64 + lane) * 8);
          s16x8 a1 = *(const s16x8*)(AFm + ((8 + kt) * 64 + lane) * 8);
          #pragma unroll
          for (int nt = 0; nt < 4; ++nt) {
            const int baddr = (nt * 16 + c16) * 512 + ((kt * 64 + quad * 16) ^ xswz);
            s16x8 b8 = *(const s16x8*)((const char*)Bs + baddr);
            acc[0][nt] = __builtin_amdgcn_mfma_f32_16x16x32_bf16(
                a0, b8, acc[0][nt], 0, 0, 0);
            acc[1][nt] = __builtin_amdgcn_mfma_f32_16x16x32_bf16(
                a1, b8, acc[1][nt], 0, 0, 0);
          }
        }

        // vd*tanh(z) = vd - vd2*rcp(e^{2z}+1); acc already 2*log2e*z
        #pragma unroll
        for (int nt = 0; nt < 4; ++nt) {
          const float v2 = vd2_s[h0 + nt * 16 + c16];
          #pragma unroll
          for (int mi = 0; mi < 2; ++mi) {
            #pragma unroll
            for (int r = 0; r < 4; ++r) {
              float e = __builtin_amdgcn_exp2f(acc[mi][nt][r]);
              sdp[mh * 2 + mi][r] += v2 * __builtin_amdgcn_rcpf(e + 1.0f);
            }
          }
        }
      }
    }

    // deferred 16-lane reduce -> d-scores into sc4[512+q]
    #pragma unroll
    for (int m = 1; m < 16; m <<= 1) vs2 += __shfl_xor(vs2, m, 64);
    #pragma unroll
    for (int mt = 0; mt < 4; ++mt)
      #pragma unroll
      for (int r = 0; r < 4; ++r) {
        float v = sdp[mt][r];
        #pragma unroll
        for (int m = 1; m < 16; m <<= 1) v += __shfl_xor(v, m, 64);
        if (c16 == 0)
          sc4[512 + wq0 + mt * 16 + quad * 4 + r] = 0.5f * vs2 - v;
      }
  }
  __syncthreads();  // Bs dead; overlay becomes fphase arrays

  { // fphase LDS loads; one exp2 per thread folds c2/m2 into multipliers
    const int r = (b * NL + p) * ND + tid;
    e2c_s[tid] = __builtin_amdgcn_exp2f(b2f(C2b[r]));
    e2m_s[tid] = __builtin_amdgcn_exp2f(-b2f(M2b[r]));
    vc2_s[tid] = 2.0f * vc[tid];
    vm2_s[tid] = 2.0f * vm[tid];
  }
  __syncthreads();

  // ======== phase 2: scores c, b, m (no exp2 in inner loop) =============
  {
    const int qsub = lane >> 4;
    const int hb = c16 * 4;
    float lc = 0.f, lm = 0.f;
    #pragma unroll
    for (int hi = 0; hi < 4; ++hi) {
      const int h = hb + hi * 64;
      #pragma unroll
      for (int i = 0; i < 4; ++i) { lc += vc2_s[h + i]; lm += vm2_s[h + i]; }
    }
    #pragma unroll
    for (int m = 1; m < 16; m <<= 1) {
      lc += __shfl_xor(lc, m, 64);
      lm += __shfl_xor(lm, m, 64);
    }
    const float c0 = 0.5f * lc, m0 = 0.5f * lm;

    for (int qg = 0; qg < 16; ++qg) {
      const int q = wave * 64 + qg * 4 + qsub;
      const float* ecr = EC1 + (b * NL + q) * NH;
      const float* emr = EM1 + (b * NL + q) * NH;
      const float* xr  = X + (b * NL + q) * ND;
      float pcr0 = 0.f, pmr0 = 0.f, pb0 = 0.f;
      float pcr1 = 0.f, pmr1 = 0.f, pb1 = 0.f;
      #pragma unroll
      for (int hi = 0; hi < 4; ++hi) {
        const int h = hb + hi * 64;
        f32x4 ec = *(const f32x4*)(ecr + h);
        f32x4 em = *(const f32x4*)(emr + h);
        f32x4 xv = *(const f32x4*)(xr + h);
        #pragma unroll
        for (int i = 0; i < 4; ++i) {
          float tc = ec[i] * e2c_s[h + i] + 1.0f;
          float tm = em[i] * e2m_s[h + i] + 1.0f;
          if (i & 1) {
            pcr1 += vc2_s[h + i] * __builtin_amdgcn_rcpf(tc);
            pmr1 += vm2_s[h + i] * __builtin_amdgcn_rcpf(tm);
            pb1 += hp_s[h + i] * xv[i];
          } else {
            pcr0 += vc2_s[h + i] * __builtin_amdgcn_rcpf(tc);
            pmr0 += vm2_s[h + i] * __builtin_amdgcn_rcpf(tm);
            pb0 += hp_s[h + i] * xv[i];
          }
        }
      }
      float pcr = pcr0 + pcr1, pmr = pmr0 + pmr1, pb = pb0 + pb1;
      #pragma unroll
      for (int m = 1; m < 16; m <<= 1) {
        pcr += __shfl_xor(pcr, m, 64);
        pmr += __shfl_xor(pmr, m, 64);
        pb  += __shfl_xor(pb, m, 64);
      }
      if (c16 == 0) {
        sc4[q]       = c0 - pcr;
        sc4[256 + q] = pb;
        sc4[768 + q] = m0 - pmr;
      }
    }
  }
  __syncthreads();

  // ======== phase 3: softmax; wave w owns branch w ======================
  {
    float s0 = sc4[wave * 256 + lane];
    float s1 = sc4[wave * 256 + lane + 64];
    float s2 = sc4[wave * 256 + lane + 128];
    float s3 = sc4[wave * 256 + lane + 192];
    float mx = fmaxf(fmaxf(s0, s1), fmaxf(s2, s3));
    #pragma unroll
    for (int m = 1; m < 64; m <<= 1) mx = fmaxf(mx, __shfl_xor(mx, m, 64));
    float e0 = __builtin_amdgcn_exp2f((s0 - mx) * LOG2E);
    float e1 = __builtin_amdgcn_exp2f((s1 - mx) * LOG2E);
    float e2 = __builtin_amdgcn_exp2f((s2 - mx) * LOG2E);
    float e3 = __builtin_amdgcn_exp2f((s3 - mx) * LOG2E);
    float sm = e0 + e1 + e2 + e3;
    #pragma unroll
    for (int m = 1; m < 64; m <<= 1) sm += __shfl_xor(sm, m, 64);
    sc4[wave * 256 + lane]       = e0;
    sc4[wave * 256 + lane + 64]  = e1;
    sc4[wave * 256 + lane + 128] = e2;
    sc4[wave * 256 + lane + 192] = e3;
    if (lane == 0) invsum[wave] = __builtin_amdgcn_rcpf(sm);
  }
  __syncthreads();

  // ======== phase 4: attend =============================================
  {
    const int q0 = wave * 64;
    f32x4 pa0 = {0.f,0.f,0.f,0.f}, pa1 = {0.f,0.f,0.f,0.f};
    f32x4 pa2 = {0.f,0.f,0.f,0.f}, pa3 = {0.f,0.f,0.f,0.f};
    for (int qi = 0; qi < 64; ++qi) {
      const int q = q0 + qi;
      const float ac = sc4[q];
      const float ab = sc4[256 + q];
      const float ad = sc4[512 + q];
      const float am = sc4[768 + q];
      f32x4 hv = *(const f32x4*)(Hq + (b * NL + q) * ND + lane * 4);
      pa0 += ac * hv; pa1 += ab * hv; pa2 += ad * hv; pa3 += am * hv;
    }
    *(f32x4*)(redp + (wave * 4 + 0) * 256 + lane * 4) = pa0;
    *(f32x4*)(redp + (wave * 4 + 1) * 256 + lane * 4) = pa1;
    *(f32x4*)(redp + (wave * 4 + 2) * 256 + lane * 4) = pa2;
    *(f32x4*)(redp + (wave * 4 + 3) * 256 + lane * 4) = pa3;
  }
  __syncthreads();

  // ======== phase 5: cross-wave reduce + normalize + store ==============
  {
    #pragma unroll
    for (int br = 0; br < 4; ++br) {
      float s = redp[(0 * 4 + br) * 256 + tid] + redp[(1 * 4 + br) * 256 + tid]
              + redp[(2 * 4 + br) * 256 + tid] + redp[(3 * 4 + br) * 256 + tid];
      out[((br * NB + b) * NL + p) * ND + tid] = s * invsum[br];
    }
  }
}

extern "C" void kernel_launch(void* const* d_in, const int* in_sizes, int n_in,
                              void* d_out, int out_size, void* d_ws, size_t ws_size,
                              hipStream_t stream) {
  const float* Hp  = (const float*)d_in[0];
  const float* Hq  = (const float*)d_in[1];
  const float* Wc1 = (const float*)d_in[2];
  const float* Wc2 = (const float*)d_in[3];
  const float* vc  = (const float*)d_in[4];
  const float* Wb  = (const float*)d_in[5];
  const float* Wd  = (const float*)d_in[6];
  const float* vd  = (const float*)d_in[7];
  const float* Wm  = (const float*)d_in[8];
  const float* vm  = (const float*)d_in[9];
  float* ws = (float*)d_ws;
  float* out = (float*)d_out;

  hipLaunchKernelGGL(prep, dim3(128, 3), dim3(256), 0, stream,
                     Hq, Wc1, Wc2, Wb, Wm, Wd, ws);
  hipLaunchKernelGGL(gemm5, dim3(16, 8, 5), dim3(256), 0, stream,
                     Hq, Hp, ws);
  hipLaunchKernelGGL(dfused, dim3(256, 4), dim3(256), 0, stream,
                     Hp, Hq, vd, vc, vm, ws, out);
}